// Round 9
// baseline (374.232 us; speedup 1.0000x reference)
//
#include <hip/hip_runtime.h>
#include <hip/hip_bf16.h>
#include <stdint.h>

#define N_NODES 50000
#define N_EDGES 1600000
#define D_IN    512
#define D_H1    256   // 4 heads * 64 concat
#define D_OUT   64

#define NBUK    196   // coarse buckets: src>>8 (256 nodes each)
#define MAXB    9216  // per-bucket region capacity (mean 8163, +11 sigma)
#define EPB     4096  // edges per partition block
#define NPB     391   // ceil(N_EDGES / EPB)
#define SLOT    96    // per-node list stride (max degree ~58, list padded to mult-8)

#define NR      50001 // rows incl. zero row
#define ZROW    50000 // reserved all-zero row index (pad target)

typedef __attribute__((ext_vector_type(8))) short  short8;   // 8 bf16 = 4 VGPRs (MFMA A/B frag)
typedef __attribute__((ext_vector_type(4))) float  f32x4;    // MFMA C/D frag
typedef __attribute__((ext_vector_type(2))) float  f32x2;
typedef __attribute__((ext_vector_type(4))) unsigned int u32x4;
typedef __attribute__((ext_vector_type(2))) unsigned int u32x2;

// address-space-qualified void for the global_load_lds builtin
typedef __attribute__((address_space(1))) void GASV;
typedef __attribute__((address_space(3))) void LASV;

static __device__ __forceinline__ unsigned short f2bf(float f) {
    union { float f; unsigned int u; } c; c.f = f;
    unsigned int u = c.u;
    return (unsigned short)((u + 0x7FFFu + ((u >> 16) & 1u)) >> 16);  // RNE
}
// HW packed convert: dst.lo = bf16(a), dst.hi = bf16(b) — 1 op replaces 6.
static __device__ __forceinline__ unsigned int cvtpk(float a, float b) {
    unsigned int r;
    asm("v_cvt_pk_bf16_f32 %0, %1, %2" : "=v"(r) : "v"(a), "v"(b));
    return r;
}
static __device__ __forceinline__ unsigned short f2bf1(float f) {
    return (unsigned short)cvtpk(f, f);
}
static __device__ __forceinline__ float uasf(unsigned int u) {
    union { unsigned int u; float f; } c; c.u = u; return c.f;
}
static __device__ __forceinline__ void glds16(const unsigned int* g, unsigned int* l) {
    __builtin_amdgcn_global_load_lds((GASV*)g, (LASV*)l, 16, 0, 0);
}

// runtime-counted vmcnt wait (immediate-only instruction -> small switch)
static __device__ __forceinline__ void waitvm(int n) {
    switch (n) {
    case 0: asm volatile("s_waitcnt vmcnt(0)" ::: "memory"); break;
    case 1: asm volatile("s_waitcnt vmcnt(1)" ::: "memory"); break;
    case 2: asm volatile("s_waitcnt vmcnt(2)" ::: "memory"); break;
    case 3: asm volatile("s_waitcnt vmcnt(3)" ::: "memory"); break;
    case 4: asm volatile("s_waitcnt vmcnt(4)" ::: "memory"); break;
    case 5: asm volatile("s_waitcnt vmcnt(5)" ::: "memory"); break;
    case 6: asm volatile("s_waitcnt vmcnt(6)" ::: "memory"); break;
    case 7: asm volatile("s_waitcnt vmcnt(7)" ::: "memory"); break;
    case 8: asm volatile("s_waitcnt vmcnt(8)" ::: "memory"); break;
    default: asm volatile("s_waitcnt vmcnt(9)" ::: "memory"); break;
    }
    __builtin_amdgcn_sched_barrier(0);
}

// ---------------- phase 1: partition edges into 196 coarse buckets ----------------

__global__ __launch_bounds__(256) void part_kernel(const int* __restrict__ src,
                                                   const int* __restrict__ dst,
                                                   int* __restrict__ gcnt,
                                                   unsigned int* __restrict__ gbuk) {
    __shared__ int hist[NBUK];
    __shared__ int lofs[NBUK];
    __shared__ int gbase[NBUK];
    __shared__ int sbuf[256];
    __shared__ unsigned int sorted[EPB];
    __shared__ unsigned char bid[EPB];

    const int t  = threadIdx.x;
    const int e0 = blockIdx.x * EPB;
    int ec = N_EDGES - e0; if (ec > EPB) ec = EPB;

    for (int i = t; i < NBUK; i += 256) hist[i] = 0;
    __syncthreads();

    unsigned int rec[16];
    int bb[16], idx[16];
#pragma unroll
    for (int j = 0; j < 16; ++j) {
        int i = j * 256 + t;
        if (i < ec) {
            int s = src[e0 + i], d = dst[e0 + i];
            int b = s >> 8;
            rec[j] = ((unsigned int)(s & 255) << 16) | (unsigned int)d;
            bb[j]  = b;
            idx[j] = atomicAdd(&hist[b], 1);
        } else bb[j] = -1;
    }
    __syncthreads();

    int v = (t < NBUK) ? hist[t] : 0;
    sbuf[t] = v;
    __syncthreads();
#pragma unroll
    for (int off = 1; off < 256; off <<= 1) {
        int x = (t >= off) ? sbuf[t - off] : 0;
        __syncthreads();
        sbuf[t] += x;
        __syncthreads();
    }
    if (t < NBUK) {
        lofs[t]  = sbuf[t] - v;
        gbase[t] = atomicAdd(&gcnt[t], v);
    }
    __syncthreads();

#pragma unroll
    for (int j = 0; j < 16; ++j) {
        if (bb[j] >= 0) {
            int p = lofs[bb[j]] + idx[j];
            sorted[p] = rec[j];
            bid[p] = (unsigned char)bb[j];
        }
    }
    __syncthreads();

    for (int i = t; i < ec; i += 256) {
        int b = bid[i];
        int p = gbase[b] + (i - lofs[b]);
        gbuk[(size_t)b * MAXB + p] = sorted[i];
    }
}

// ---------------- phase 2: per-bucket LDS counting sort -> per-node padded lists ----------------

__global__ __launch_bounds__(256) void sort_kernel(const int* __restrict__ gcnt,
                                                   const unsigned int* __restrict__ gbuk,
                                                   unsigned short* __restrict__ sdst,
                                                   int* __restrict__ deg) {
    __shared__ int hist[256];
    __shared__ int nofs[256];
    __shared__ int sbuf[256];
    __shared__ unsigned short list[MAXB];

    const int t = threadIdx.x;
    const int b = blockIdx.x;
    const int cnt = gcnt[b];
    const unsigned int* buk = gbuk + (size_t)b * MAXB;

    hist[t] = 0;
    __syncthreads();
    for (int i = t; i < cnt; i += 256)
        atomicAdd(&hist[buk[i] >> 16], 1);
    __syncthreads();

    int v = hist[t];
    sbuf[t] = v;
    __syncthreads();
#pragma unroll
    for (int off = 1; off < 256; off <<= 1) {
        int x = (t >= off) ? sbuf[t - off] : 0;
        __syncthreads();
        sbuf[t] += x;
        __syncthreads();
    }
    nofs[t] = sbuf[t] - v;
    const int n = b * 256 + t;
    if (n < N_NODES) deg[n] = v;
    __syncthreads();

    for (int i = t; i < cnt; i += 256) {
        unsigned int r = buk[i];
        int p = atomicAdd(&nofs[r >> 16], 1);
        list[p] = (unsigned short)(r & 0xffffu);
    }
    __syncthreads();

    // cooperative coalesced writeout: 8 lanes per node, pad to mult-8 with ZROW
    for (int base = 0; base < 256; base += 32) {
        int node = base + (t >> 3);
        int l8   = t & 7;
        int vv   = hist[node];
        int beg  = nofs[node] - vv;
        int n2   = b * 256 + node;
        if (n2 < N_NODES) {
            int words = ((vv + 7) & ~7) >> 1;
            unsigned int* out32 = (unsigned int*)(sdst + (size_t)n2 * SLOT);
            for (int j2 = l8; j2 < words; j2 += 8) {
                unsigned int lo = (2 * j2     < vv) ? list[beg + 2 * j2]     : (unsigned int)ZROW;
                unsigned int hi = (2 * j2 + 1 < vv) ? list[beg + 2 * j2 + 1] : (unsigned int)ZROW;
                out32[j2] = lo | (hi << 16);
            }
        }
    }
}

// ---------------- weight repack + zero-row init ----------------

__global__ void convw_kernel(const float* __restrict__ W1, const float* __restrict__ W2,
                             unsigned short* __restrict__ Bt1, unsigned short* __restrict__ Bt2,
                             unsigned short* __restrict__ t1, unsigned short* __restrict__ t2) {
    int i = blockIdx.x * 256 + threadIdx.x;
    if (i < 4 * 512 * 64) {                 // W1[h][k][j] -> Bt1[(h*64+j)][k]
        int h = i >> 15;
        int k = (i >> 6) & 511;
        int j = i & 63;
        Bt1[(h * 64 + j) * 512 + k] = f2bf(W1[i]);
    } else if (i < 4 * 512 * 64 + 256 * 64) {
        int r = i - 4 * 512 * 64;           // W2[k][n] -> Bt2[n][k]
        int k = r >> 6;
        int n = r & 63;
        Bt2[n * 256 + k] = f2bf(W2[r]);
    } else {
        int r = i - (4 * 512 * 64 + 256 * 64);
        if (r < 256) {                      // zero row of t1
            t1[(size_t)ZROW * 256 + r] = 0;
        } else if (r < 256 + 64) {          // zero row of t2
            t2[(size_t)ZROW * 64 + (r - 256)] = 0;
        }
    }
}

// ---------------- GEMM1: t1[NR][256] = X[M][512] @ Bt1[256][512]^T (row-major out) ----------------

__global__ __launch_bounds__(512) void gemm1_kernel(const float* __restrict__ A,
                                                    const unsigned short* __restrict__ Bt,
                                                    unsigned short* __restrict__ C) {
    constexpr int BM = 128, BK = 32, LDK = 40, K = D_IN, M = N_NODES;
    __shared__ unsigned short As[BM * LDK];   // 10.0 KB
    __shared__ unsigned short Bs[256 * LDK];  // 20.0 KB

    const int tid  = threadIdx.x;
    const int lane = tid & 63;
    const int w    = tid >> 6;
    const int wm   = (w >> 2) * 64;
    const int wn   = (w & 3) * 64;
    const int quad = lane >> 4;
    const int l15  = lane & 15;
    const int bm   = blockIdx.x;

    f32x4 acc[4][4];
#pragma unroll
    for (int mi = 0; mi < 4; ++mi)
#pragma unroll
        for (int ni = 0; ni < 4; ++ni)
            acc[mi][ni] = (f32x4){0.f, 0.f, 0.f, 0.f};

    const int r0 = tid >> 2;
    const int f8 = tid & 3;

    for (int k0 = 0; k0 < K; k0 += BK) {
        {   // stage A (128 x 32 fp32 -> bf16), HW pack-convert
            int grow = bm * BM + r0;
            if (grow >= M) grow = M - 1;
            const float* ap = A + (size_t)grow * K + k0 + f8 * 8;
            f32x4 v0 = *(const f32x4*)ap;
            f32x4 v1 = *(const f32x4*)(ap + 4);
            u32x4 pk;
            pk[0] = cvtpk(v0[0], v0[1]);
            pk[1] = cvtpk(v0[2], v0[3]);
            pk[2] = cvtpk(v1[0], v1[1]);
            pk[3] = cvtpk(v1[2], v1[3]);
            *(u32x4*)&As[r0 * LDK + f8 * 8] = pk;
        }
        {   // stage B (256 x 32 bf16)
#pragma unroll
            for (int p = 0; p < 2; ++p) {
                int row = p * 128 + r0;
                u32x4 v = *(const u32x4*)(Bt + (size_t)row * K + k0 + f8 * 8);
                *(u32x4*)&Bs[row * LDK + f8 * 8] = v;
            }
        }
        __syncthreads();

        short8 af[4], bfr[4];
#pragma unroll
        for (int mi = 0; mi < 4; ++mi)
            af[mi] = *(const short8*)&As[(wm + mi * 16 + l15) * LDK + quad * 8];
#pragma unroll
        for (int ni = 0; ni < 4; ++ni)
            bfr[ni] = *(const short8*)&Bs[(wn + ni * 16 + l15) * LDK + quad * 8];
#pragma unroll
        for (int mi = 0; mi < 4; ++mi)
#pragma unroll
            for (int ni = 0; ni < 4; ++ni)
                acc[mi][ni] = __builtin_amdgcn_mfma_f32_16x16x32_bf16(af[mi], bfr[ni], acc[mi][ni], 0, 0, 0);
        __syncthreads();
    }

#pragma unroll
    for (int mi = 0; mi < 4; ++mi) {
        int row0 = bm * BM + wm + mi * 16 + quad * 4;
#pragma unroll
        for (int ni = 0; ni < 4; ++ni) {
            int col = wn + ni * 16 + l15;
#pragma unroll
            for (int r = 0; r < 4; ++r) {
                int row = row0 + r;
                if (row < M) C[(size_t)row * 256 + col] = f2bf1(acc[mi][ni][r]);
            }
        }
    }
}

// ---------------- aggF: fused agg1 + gemm2 (full-row contiguous DMA gather) ----------------
// R8 measured 8.4 TB/s aggregate on full-row gathers vs ~9 TB/s empirical gather ceiling
// (R4: 9.5). Remaining waste is pad8 (35.6 rows/node gathered vs 32.5 at pad2). This round:
// full chunks (4 DMAs = 8 rows) unchanged; tail chunk issues only rows2&3 2-row DMAs with a
// dynamic consume bound. Lists stay mult-8 ZROW-padded (sort unchanged) so odd-deg's extra
// row is a zero row and agg2's pad8 reads stay safe.

__global__ __launch_bounds__(256) void aggf_kernel(const unsigned short* __restrict__ t1,
                                                   const int* __restrict__ deg,
                                                   const unsigned short* __restrict__ sdst,
                                                   const unsigned short* __restrict__ Bt2,
                                                   unsigned short* __restrict__ t2) {
    __shared__ __align__(16) unsigned int ring[4][2][1024];   // 4 waves x 2 bufs x 4KB = 32KB
    __shared__ __align__(16) unsigned short h_lds[16][264];   // 528B rows (bank-spread), 8.25KB

    const int w    = __builtin_amdgcn_readfirstlane(threadIdx.x >> 6);
    const int lane = threadIdx.x & 63;
    const int s0b  = blockIdx.x * 16;
    const int s0   = s0b + w * 4;
    const unsigned int* tb32 = (const unsigned int*)t1;
    const unsigned int loff = ((unsigned)(lane & 31)) << 2;   // 16B chunk within a 512B row

    const int end0 = deg[s0 + 0], end1 = deg[s0 + 1], end2 = deg[s0 + 2], end3 = deg[s0 + 3];
    const int elv0 = sdst[(size_t)(s0 + 0) * SLOT + lane];
    const int elv1 = sdst[(size_t)(s0 + 1) * SLOT + lane];
    const int elv2 = sdst[(size_t)(s0 + 2) * SLOT + lane];
    const int elv3 = sdst[(size_t)(s0 + 3) * SLOT + lane];
    asm volatile("" :: "v"(end0), "v"(end1), "v"(end2), "v"(end3),
                       "v"(elv0), "v"(elv1), "v"(elv2), "v"(elv3));

#define AGGF_ISSUE_FULL(ELV, C, B)                                                      \
    {                                                                                   \
        int q  = ((C) << 3) + (lane >> 5);                                              \
        int ra = __shfl(ELV, q);                                                        \
        int rb_ = __shfl(ELV, q + 2);                                                   \
        int rc = __shfl(ELV, q + 4);                                                    \
        int rd = __shfl(ELV, q + 6);                                                    \
        unsigned int* dp = &ring[w][B][0];                                              \
        glds16(tb32 + (unsigned)ra  * 128u + loff, dp);                                 \
        glds16(tb32 + (unsigned)rb_ * 128u + loff, dp + 256);                           \
        glds16(tb32 + (unsigned)rc  * 128u + loff, dp + 512);                           \
        glds16(tb32 + (unsigned)rd  * 128u + loff, dp + 768);                           \
    }

#define AGGF_ISSUE_TAIL(ELV, C, B, TQ)                                                  \
    {                                                                                   \
        for (int d = 0; d < (TQ); ++d) {                                                \
            int r = __shfl(ELV, ((C) << 3) + (d << 1) + (lane >> 5));                   \
            glds16(tb32 + (unsigned)r * 128u + loff, &ring[w][B][d << 8]);              \
        }                                                                               \
    }

#define AGGF_CONSUME(B, RC)                                                             \
    {                                                                                   \
        const unsigned int* rbp = &ring[w][B][lane << 1];                               \
        for (int r = 0; r < (RC); ++r) {                                                \
            u32x2 v = *(const u32x2*)(rbp + (r << 7));                                  \
            a0 += uasf(v[0] << 16); a1 += uasf(v[0] & 0xffff0000u);                     \
            a2 += uasf(v[1] << 16); a3 += uasf(v[1] & 0xffff0000u);                     \
        }                                                                               \
    }

#define AGGF_NODE(J)                                                                    \
    {                                                                                   \
        const int end   = end##J;                                                       \
        const int rows2 = (end + 1) >> 1;       /* 2-row units (pad2) */                \
        const int nfull = rows2 >> 2;           /* full 4-DMA chunks */                 \
        const int tq2   = rows2 & 3;            /* tail 2-row DMAs */                   \
        const int ncht  = nfull + (tq2 ? 1 : 0);                                        \
        float a0 = 0.f, a1 = 0.f, a2 = 0.f, a3 = 0.f;                                   \
        if (ncht > 0) {                                                                 \
            if (nfull > 0) { AGGF_ISSUE_FULL(elv##J, 0, 0); }                           \
            else           { AGGF_ISSUE_TAIL(elv##J, 0, 0, tq2); }                      \
            for (int c = 1; c < ncht; ++c) {                                            \
                int nc;                                                                 \
                if (c < nfull) { AGGF_ISSUE_FULL(elv##J, c, c & 1); nc = 4; }           \
                else           { AGGF_ISSUE_TAIL(elv##J, c, c & 1, tq2); nc = tq2; }    \
                waitvm(nc);                                                             \
                AGGF_CONSUME((c - 1) & 1, 8);                                           \
            }                                                                           \
            waitvm(0);                                                                  \
            AGGF_CONSUME((ncht - 1) & 1, (tq2 ? (tq2 << 1) : 8));                       \
        }                                                                               \
        float iv = (end > 0) ? (1.0f / (float)end) : 0.f;                               \
        float m0 = a0 * iv, m1 = a1 * iv, m2 = a2 * iv, m3 = a3 * iv;                   \
        m0 = (m0 > 0.f) ? m0 : (__expf(m0) - 1.f);                                      \
        m1 = (m1 > 0.f) ? m1 : (__expf(m1) - 1.f);                                      \
        m2 = (m2 > 0.f) ? m2 : (__expf(m2) - 1.f);                                      \
        m3 = (m3 > 0.f) ? m3 : (__expf(m3) - 1.f);                                      \
        u32x2 hw;                                                                       \
        hw[0] = cvtpk(m0, m1);                                                          \
        hw[1] = cvtpk(m2, m3);                                                          \
        *(u32x2*)&h_lds[(w << 2) + J][lane << 2] = hw;                                  \
    }

    AGGF_NODE(0);
    AGGF_NODE(1);
    AGGF_NODE(2);
    AGGF_NODE(3);

    __syncthreads();

    // fused gemm2: t2[16 nodes][64] = h[16][256] @ Bt2[64][256]^T ; wave w owns 16 cols
    {
        const int l15 = lane & 15, quad = lane >> 4;
        f32x4 acc = (f32x4){0.f, 0.f, 0.f, 0.f};
#pragma unroll
        for (int st = 0; st < 8; ++st) {
            short8 afr = *(const short8*)&h_lds[l15][st * 32 + quad * 8];
            short8 bfr = *(const short8*)(Bt2 + (size_t)(w * 16 + l15) * 256 + st * 32 + quad * 8);
            acc = __builtin_amdgcn_mfma_f32_16x16x32_bf16(afr, bfr, acc, 0, 0, 0);
        }
#pragma unroll
        for (int r = 0; r < 4; ++r)
            t2[(size_t)(s0b + quad * 4 + r) * 64 + w * 16 + l15] = f2bf1(acc[r]);
    }
}

// ---------------- agg2: deep-pipelined full-row DMA gather over t2 (128B rows) ----------------
// R8's agg2 kept only 1-2 KB in flight per wave (vmcnt(1), 2-deep) -> latency-bound.
// Now: issue ALL of a node's <=8 1KB-DMAs up-front, cross-node counted-vmcnt pipeline
// (R4 pattern). 2 x 8KB buffers per wave (64 KB LDS, 2 blocks/CU) -> ~16 KB in flight
// per wave, comfortably covering L2/L3 latency; becomes bytes-bound (~228 MB @ wall).

__global__ __launch_bounds__(256) void agg2_kernel(const unsigned short* __restrict__ t2,
                                                   const int* __restrict__ deg,
                                                   const unsigned short* __restrict__ sdst,
                                                   float* __restrict__ out) {
    __shared__ __align__(16) unsigned int ring2[4][2][2048];  // 4 waves x 2 bufs x 8KB = 64KB

    const int w    = __builtin_amdgcn_readfirstlane(threadIdx.x >> 6);
    const int lane = threadIdx.x & 63;
    const int s0   = blockIdx.x * 16 + w * 4;
    const unsigned int* tb32 = (const unsigned int*)t2;
    const unsigned int loff = ((unsigned)(lane & 7)) << 2;    // 16B chunk within a 128B row

    const int end0 = deg[s0 + 0], end1 = deg[s0 + 1], end2 = deg[s0 + 2], end3 = deg[s0 + 3];
    const int elv0 = sdst[(size_t)(s0 + 0) * SLOT + lane];
    const int elv1 = sdst[(size_t)(s0 + 1) * SLOT + lane];
    const int elv2 = sdst[(size_t)(s0 + 2) * SLOT + lane];
    const int elv3 = sdst[(size_t)(s0 + 3) * SLOT + lane];
    asm volatile("" :: "v"(end0), "v"(end1), "v"(end2), "v"(end3),
                       "v"(elv0), "v"(elv1), "v"(elv2), "v"(elv3));

    // each DMA: 64 lanes x 16B = 1KB = 8 rows of 128B; lane>>3 = row, lane&7 = 16B chunk
#define A2_ISSUE(J, B, NJ)                                                              \
    int NJ;                                                                             \
    {                                                                                   \
        const int nd = ((end##J + 7) & ~7) >> 3;     /* <= 8 DMAs */                    \
        for (int d = 0; d < nd; ++d) {                                                  \
            int r = __shfl(elv##J, (d << 3) + (lane >> 3));                             \
            glds16(tb32 + (unsigned)r * 32u + loff, &ring2[w][B][d << 8]);              \
        }                                                                               \
        NJ = nd;                                                                        \
    }

    // row r (0..nr), u32-col c: lds idx = (r>>3)<<8 | (r&7)<<5 | c
#define A2_CONSUME(J, B)                                                                \
    {                                                                                   \
        const int end = end##J;                                                         \
        const int nr  = (end + 7) & ~7;                                                 \
        const int c   = lane & 31;                                                      \
        float a0 = 0.f, a1 = 0.f;                                                       \
        for (int r = lane >> 5; r < nr; r += 2) {                                       \
            unsigned int v = ring2[w][B][(((r >> 3) << 8) | ((r & 7) << 5)) + c];       \
            a0 += uasf(v << 16); a1 += uasf(v & 0xffff0000u);                           \
        }                                                                               \
        a0 += __shfl_xor(a0, 32);                                                       \
        a1 += __shfl_xor(a1, 32);                                                       \
        if (lane < 32) {                                                                \
            float iv = (end > 0) ? (1.0f / (float)end) : 0.f;                           \
            f32x2 rr; rr.x = a0 * iv; rr.y = a1 * iv;                                   \
            *(f32x2*)(out + (size_t)(s0 + J) * D_OUT + c * 2) = rr;                     \
        }                                                                               \
        __builtin_amdgcn_sched_barrier(0);                                              \
    }

    A2_ISSUE(0, 0, n0i);
    A2_ISSUE(1, 1, n1i); waitvm(n1i);         // node0 loads landed (n1 newest in flight)
    A2_CONSUME(0, 0);                         // ends with 1 global store
    A2_ISSUE(2, 0, n2i); waitvm(n2i + 1);     // +1: store(0) may still be outstanding
    A2_CONSUME(1, 1);
    A2_ISSUE(3, 1, n3i); waitvm(n3i + 1);
    A2_CONSUME(2, 0);
    waitvm(1);                                // node3 loads done (store(2) may remain)
    A2_CONSUME(3, 1);
}

// ---------------- launch ----------------

extern "C" void kernel_launch(void* const* d_in, const int* in_sizes, int n_in,
                              void* d_out, int out_size, void* d_ws, size_t ws_size,
                              hipStream_t stream) {
    const float* X  = (const float*)d_in[0];
    const int*   ei = (const int*)d_in[1];
    const float* W1 = (const float*)d_in[2];
    const float* W2 = (const float*)d_in[3];
    const int* src = ei;             // edge_index[0] = segment ids
    const int* dst = ei + N_EDGES;   // edge_index[1] = gathered neighbors

    char* ws = (char*)d_ws;
    size_t off = 0;
    auto alloc = [&](size_t bytes) {
        off = (off + 255) & ~(size_t)255;
        void* p = ws + off;
        off += bytes;
        return p;
    };
    int*          gcnt = (int*)alloc((size_t)NBUK * 4);
    unsigned int* gbuk = (unsigned int*)alloc((size_t)NBUK * MAXB * 4);
    unsigned short* sdst = (unsigned short*)alloc(((size_t)N_NODES * SLOT + 64) * 2);
    int*          deg  = (int*)alloc((size_t)N_NODES * 4);
    unsigned short* Bt1 = (unsigned short*)alloc((size_t)D_H1 * D_IN * 2);
    unsigned short* Bt2 = (unsigned short*)alloc((size_t)D_OUT * D_H1 * 2);
    unsigned short* t1  = (unsigned short*)alloc((size_t)NR * D_H1 * 2);
    unsigned short* t2  = (unsigned short*)alloc((size_t)NR * D_OUT * 2);

    hipMemsetAsync(gcnt, 0, (size_t)NBUK * 4, stream);

    part_kernel<<<NPB, 256, 0, stream>>>(src, dst, gcnt, gbuk);
    sort_kernel<<<NBUK, 256, 0, stream>>>(gcnt, gbuk, sdst, deg);
    convw_kernel<<<(4 * 512 * 64 + 256 * 64 + 256 + 64 + 255) / 256, 256, 0, stream>>>(
        W1, W2, Bt1, Bt2, t1, t2);

    gemm1_kernel<<<(N_NODES + 127) / 128, 512, 0, stream>>>(X, Bt1, t1);
    aggf_kernel<<<N_NODES / 16, 256, 0, stream>>>(t1, deg, sdst, Bt2, t2);
    agg2_kernel<<<N_NODES / 16, 256, 0, stream>>>(t2, deg, sdst, (float*)d_out);
}

// Round 10
// 351.784 us; speedup vs baseline: 1.0638x; 1.0638x over previous
//
#include <hip/hip_runtime.h>
#include <hip/hip_bf16.h>
#include <stdint.h>

#define N_NODES 50000
#define N_EDGES 1600000
#define D_IN    512
#define D_H1    256   // 4 heads * 64 concat
#define D_OUT   64

#define NBUK    196   // coarse buckets: src>>8 (256 nodes each)
#define MAXB    9216  // per-bucket region capacity (mean 8163, +11 sigma)
#define EPB     4096  // edges per partition block
#define NPB     391   // ceil(N_EDGES / EPB)
#define SLOT    96    // per-node list stride (max degree ~58, list padded to mult-8)

#define NR      50001 // rows incl. zero row
#define ZROW    50000 // reserved all-zero row index (pad target)

typedef __attribute__((ext_vector_type(8))) short  short8;   // 8 bf16 = 4 VGPRs (MFMA A/B frag)
typedef __attribute__((ext_vector_type(4))) float  f32x4;    // MFMA C/D frag
typedef __attribute__((ext_vector_type(2))) float  f32x2;
typedef __attribute__((ext_vector_type(4))) unsigned int u32x4;
typedef __attribute__((ext_vector_type(2))) unsigned int u32x2;

// address-space-qualified void for the global_load_lds builtin
typedef __attribute__((address_space(1))) void GASV;
typedef __attribute__((address_space(3))) void LASV;

static __device__ __forceinline__ unsigned short f2bf(float f) {
    union { float f; unsigned int u; } c; c.f = f;
    unsigned int u = c.u;
    return (unsigned short)((u + 0x7FFFu + ((u >> 16) & 1u)) >> 16);  // RNE
}
// HW packed convert: dst.lo = bf16(a), dst.hi = bf16(b) — 1 op replaces 6.
static __device__ __forceinline__ unsigned int cvtpk(float a, float b) {
    unsigned int r;
    asm("v_cvt_pk_bf16_f32 %0, %1, %2" : "=v"(r) : "v"(a), "v"(b));
    return r;
}
static __device__ __forceinline__ unsigned short f2bf1(float f) {
    return (unsigned short)cvtpk(f, f);
}
static __device__ __forceinline__ float uasf(unsigned int u) {
    union { unsigned int u; float f; } c; c.u = u; return c.f;
}
static __device__ __forceinline__ void glds16(const unsigned int* g, unsigned int* l) {
    __builtin_amdgcn_global_load_lds((GASV*)g, (LASV*)l, 16, 0, 0);
}

// ---------------- phase 1: partition edges into 196 coarse buckets ----------------

__global__ __launch_bounds__(256) void part_kernel(const int* __restrict__ src,
                                                   const int* __restrict__ dst,
                                                   int* __restrict__ gcnt,
                                                   unsigned int* __restrict__ gbuk) {
    __shared__ int hist[NBUK];
    __shared__ int lofs[NBUK];
    __shared__ int gbase[NBUK];
    __shared__ int sbuf[256];
    __shared__ unsigned int sorted[EPB];
    __shared__ unsigned char bid[EPB];

    const int t  = threadIdx.x;
    const int e0 = blockIdx.x * EPB;
    int ec = N_EDGES - e0; if (ec > EPB) ec = EPB;

    for (int i = t; i < NBUK; i += 256) hist[i] = 0;
    __syncthreads();

    unsigned int rec[16];
    int bb[16], idx[16];
#pragma unroll
    for (int j = 0; j < 16; ++j) {
        int i = j * 256 + t;
        if (i < ec) {
            int s = src[e0 + i], d = dst[e0 + i];
            int b = s >> 8;
            rec[j] = ((unsigned int)(s & 255) << 16) | (unsigned int)d;
            bb[j]  = b;
            idx[j] = atomicAdd(&hist[b], 1);
        } else bb[j] = -1;
    }
    __syncthreads();

    int v = (t < NBUK) ? hist[t] : 0;
    sbuf[t] = v;
    __syncthreads();
#pragma unroll
    for (int off = 1; off < 256; off <<= 1) {
        int x = (t >= off) ? sbuf[t - off] : 0;
        __syncthreads();
        sbuf[t] += x;
        __syncthreads();
    }
    if (t < NBUK) {
        lofs[t]  = sbuf[t] - v;
        gbase[t] = atomicAdd(&gcnt[t], v);
    }
    __syncthreads();

#pragma unroll
    for (int j = 0; j < 16; ++j) {
        if (bb[j] >= 0) {
            int p = lofs[bb[j]] + idx[j];
            sorted[p] = rec[j];
            bid[p] = (unsigned char)bb[j];
        }
    }
    __syncthreads();

    for (int i = t; i < ec; i += 256) {
        int b = bid[i];
        int p = gbase[b] + (i - lofs[b]);
        gbuk[(size_t)b * MAXB + p] = sorted[i];
    }
}

// ---------------- phase 2: per-bucket LDS counting sort -> per-node padded lists ----------------

__global__ __launch_bounds__(256) void sort_kernel(const int* __restrict__ gcnt,
                                                   const unsigned int* __restrict__ gbuk,
                                                   unsigned short* __restrict__ sdst,
                                                   int* __restrict__ deg) {
    __shared__ int hist[256];
    __shared__ int nofs[256];
    __shared__ int sbuf[256];
    __shared__ unsigned short list[MAXB];

    const int t = threadIdx.x;
    const int b = blockIdx.x;
    const int cnt = gcnt[b];
    const unsigned int* buk = gbuk + (size_t)b * MAXB;

    hist[t] = 0;
    __syncthreads();
    for (int i = t; i < cnt; i += 256)
        atomicAdd(&hist[buk[i] >> 16], 1);
    __syncthreads();

    int v = hist[t];
    sbuf[t] = v;
    __syncthreads();
#pragma unroll
    for (int off = 1; off < 256; off <<= 1) {
        int x = (t >= off) ? sbuf[t - off] : 0;
        __syncthreads();
        sbuf[t] += x;
        __syncthreads();
    }
    nofs[t] = sbuf[t] - v;
    const int n = b * 256 + t;
    if (n < N_NODES) deg[n] = v;
    __syncthreads();

    for (int i = t; i < cnt; i += 256) {
        unsigned int r = buk[i];
        int p = atomicAdd(&nofs[r >> 16], 1);
        list[p] = (unsigned short)(r & 0xffffu);
    }
    __syncthreads();

    // cooperative coalesced writeout: 8 lanes per node, pad to mult-8 with ZROW
    // (deg==0 nodes get a full 8-entry ZROW list so downstream pipelines stay uniform)
    for (int base = 0; base < 256; base += 32) {
        int node = base + (t >> 3);
        int l8   = t & 7;
        int vv   = hist[node];
        int beg  = nofs[node] - vv;
        int n2   = b * 256 + node;
        if (n2 < N_NODES) {
            int words = ((vv + 7) & ~7) >> 1;
            if (words == 0) words = 4;
            unsigned int* out32 = (unsigned int*)(sdst + (size_t)n2 * SLOT);
            for (int j2 = l8; j2 < words; j2 += 8) {
                unsigned int lo = (2 * j2     < vv) ? list[beg + 2 * j2]     : (unsigned int)ZROW;
                unsigned int hi = (2 * j2 + 1 < vv) ? list[beg + 2 * j2 + 1] : (unsigned int)ZROW;
                out32[j2] = lo | (hi << 16);
            }
        }
    }
}

// ---------------- weight repack + zero-row init ----------------

__global__ void convw_kernel(const float* __restrict__ W1, const float* __restrict__ W2,
                             unsigned short* __restrict__ Bt1, unsigned short* __restrict__ Bt2,
                             unsigned short* __restrict__ t1, unsigned short* __restrict__ t2) {
    int i = blockIdx.x * 256 + threadIdx.x;
    if (i < 4 * 512 * 64) {                 // W1[h][k][j] -> Bt1[(h*64+j)][k]
        int h = i >> 15;
        int k = (i >> 6) & 511;
        int j = i & 63;
        Bt1[(h * 64 + j) * 512 + k] = f2bf(W1[i]);
    } else if (i < 4 * 512 * 64 + 256 * 64) {
        int r = i - 4 * 512 * 64;           // W2[k][n] -> Bt2[n][k]
        int k = r >> 6;
        int n = r & 63;
        Bt2[n * 256 + k] = f2bf(W2[r]);
    } else {
        int r = i - (4 * 512 * 64 + 256 * 64);
        if (r < 256) {                      // zero row of t1
            t1[(size_t)ZROW * 256 + r] = 0;
        } else if (r < 256 + 64) {          // zero row of t2
            t2[(size_t)ZROW * 64 + (r - 256)] = 0;
        }
    }
}

// ---------------- GEMM1: t1[NR][256] = X[M][512] @ Bt1[256][512]^T (row-major out) ----------------

__global__ __launch_bounds__(512) void gemm1_kernel(const float* __restrict__ A,
                                                    const unsigned short* __restrict__ Bt,
                                                    unsigned short* __restrict__ C) {
    constexpr int BM = 128, BK = 32, LDK = 40, K = D_IN, M = N_NODES;
    __shared__ unsigned short As[BM * LDK];   // 10.0 KB
    __shared__ unsigned short Bs[256 * LDK];  // 20.0 KB

    const int tid  = threadIdx.x;
    const int lane = tid & 63;
    const int w    = tid >> 6;
    const int wm   = (w >> 2) * 64;
    const int wn   = (w & 3) * 64;
    const int quad = lane >> 4;
    const int l15  = lane & 15;
    const int bm   = blockIdx.x;

    f32x4 acc[4][4];
#pragma unroll
    for (int mi = 0; mi < 4; ++mi)
#pragma unroll
        for (int ni = 0; ni < 4; ++ni)
            acc[mi][ni] = (f32x4){0.f, 0.f, 0.f, 0.f};

    const int r0 = tid >> 2;
    const int f8 = tid & 3;

    for (int k0 = 0; k0 < K; k0 += BK) {
        {   // stage A (128 x 32 fp32 -> bf16), HW pack-convert
            int grow = bm * BM + r0;
            if (grow >= M) grow = M - 1;
            const float* ap = A + (size_t)grow * K + k0 + f8 * 8;
            f32x4 v0 = *(const f32x4*)ap;
            f32x4 v1 = *(const f32x4*)(ap + 4);
            u32x4 pk;
            pk[0] = cvtpk(v0[0], v0[1]);
            pk[1] = cvtpk(v0[2], v0[3]);
            pk[2] = cvtpk(v1[0], v1[1]);
            pk[3] = cvtpk(v1[2], v1[3]);
            *(u32x4*)&As[r0 * LDK + f8 * 8] = pk;
        }
        {   // stage B (256 x 32 bf16)
#pragma unroll
            for (int p = 0; p < 2; ++p) {
                int row = p * 128 + r0;
                u32x4 v = *(const u32x4*)(Bt + (size_t)row * K + k0 + f8 * 8);
                *(u32x4*)&Bs[row * LDK + f8 * 8] = v;
            }
        }
        __syncthreads();

        short8 af[4], bfr[4];
#pragma unroll
        for (int mi = 0; mi < 4; ++mi)
            af[mi] = *(const short8*)&As[(wm + mi * 16 + l15) * LDK + quad * 8];
#pragma unroll
        for (int ni = 0; ni < 4; ++ni)
            bfr[ni] = *(const short8*)&Bs[(wn + ni * 16 + l15) * LDK + quad * 8];
#pragma unroll
        for (int mi = 0; mi < 4; ++mi)
#pragma unroll
            for (int ni = 0; ni < 4; ++ni)
                acc[mi][ni] = __builtin_amdgcn_mfma_f32_16x16x32_bf16(af[mi], bfr[ni], acc[mi][ni], 0, 0, 0);
        __syncthreads();
    }

#pragma unroll
    for (int mi = 0; mi < 4; ++mi) {
        int row0 = bm * BM + wm + mi * 16 + quad * 4;
#pragma unroll
        for (int ni = 0; ni < 4; ++ni) {
            int col = wn + ni * 16 + l15;
#pragma unroll
            for (int r = 0; r < 4; ++r) {
                int row = row0 + r;
                if (row < M) C[(size_t)row * 256 + col] = f2bf1(acc[mi][ni][r]);
            }
        }
    }
}

// ---------------- aggF: fused agg1 + gemm2, continuous cross-node DMA pipeline ----------------
// R8 structure (uniform pad8 chunks of 4x 2-row DMAs, proven 8.4 TB/s) with ONE change:
// the 4 per-node vmcnt(0) drains are replaced by a single continuous chunk stream across
// all 4 nodes -- issue chunk k, vmcnt(4), consume chunk k-1; buffer parity = running chunk
// counter; node epilogues fire in-stream when a node's last chunk is consumed; one drain
// at the very end. In-flight never drops to zero mid-wave.

__global__ __launch_bounds__(256) void aggf_kernel(const unsigned short* __restrict__ t1,
                                                   const int* __restrict__ deg,
                                                   const unsigned short* __restrict__ sdst,
                                                   const unsigned short* __restrict__ Bt2,
                                                   unsigned short* __restrict__ t2) {
    __shared__ __align__(16) unsigned int ring[4][2][1024];   // 4 waves x 2 bufs x 4KB = 32KB
    __shared__ __align__(16) unsigned short h_lds[16][264];   // 528B rows (bank-spread), 8.25KB

    const int w    = __builtin_amdgcn_readfirstlane(threadIdx.x >> 6);
    const int lane = threadIdx.x & 63;
    const int s0b  = blockIdx.x * 16;
    const int s0   = s0b + w * 4;
    const unsigned int* tb32 = (const unsigned int*)t1;
    const unsigned int loff = ((unsigned)(lane & 31)) << 2;   // 16B chunk within a 512B row

    const int end0 = deg[s0 + 0], end1 = deg[s0 + 1], end2 = deg[s0 + 2], end3 = deg[s0 + 3];
    const int elv0 = sdst[(size_t)(s0 + 0) * SLOT + lane];
    const int elv1 = sdst[(size_t)(s0 + 1) * SLOT + lane];
    const int elv2 = sdst[(size_t)(s0 + 2) * SLOT + lane];
    const int elv3 = sdst[(size_t)(s0 + 3) * SLOT + lane];
    // force all prologue loads complete so compiler waits don't drain DMA counts mid-pipe
    asm volatile("" :: "v"(end0), "v"(end1), "v"(end2), "v"(end3),
                       "v"(elv0), "v"(elv1), "v"(elv2), "v"(elv3));

    const int nch0 = end0 ? (end0 + 7) >> 3 : 1;   // uniform pad8 chunks, >= 1
    const int nch1 = end1 ? (end1 + 7) >> 3 : 1;
    const int nch2 = end2 ? (end2 + 7) >> 3 : 1;
    const int nch3 = end3 ? (end3 + 7) >> 3 : 1;

#define AGGF_ISSUE(ELV, C, B)                                                           \
    {                                                                                   \
        int q  = ((C) << 3) + (lane >> 5);                                              \
        int ra = __shfl(ELV, q);                                                        \
        int rb_ = __shfl(ELV, q + 2);                                                   \
        int rc = __shfl(ELV, q + 4);                                                    \
        int rd = __shfl(ELV, q + 6);                                                    \
        unsigned int* dp = &ring[w][B][0];                                              \
        glds16(tb32 + (unsigned)ra  * 128u + loff, dp);                                 \
        glds16(tb32 + (unsigned)rb_ * 128u + loff, dp + 256);                           \
        glds16(tb32 + (unsigned)rc  * 128u + loff, dp + 512);                           \
        glds16(tb32 + (unsigned)rd  * 128u + loff, dp + 768);                           \
    }

#define AGGF_CONS(B)                                                                    \
    {                                                                                   \
        const unsigned int* rbp = &ring[w][B][lane << 1];                               \
        _Pragma("unroll")                                                               \
        for (int r = 0; r < 8; ++r) {                                                   \
            u32x2 v = *(const u32x2*)(rbp + (r << 7));                                  \
            a0 += uasf(v[0] << 16); a1 += uasf(v[0] & 0xffff0000u);                     \
            a2 += uasf(v[1] << 16); a3 += uasf(v[1] & 0xffff0000u);                     \
        }                                                                               \
    }

#define AGGF_EPI(J)                                                                     \
    {                                                                                   \
        float iv = (end##J > 0) ? (1.0f / (float)end##J) : 0.f;                         \
        float m0 = a0 * iv, m1 = a1 * iv, m2 = a2 * iv, m3 = a3 * iv;                   \
        m0 = (m0 > 0.f) ? m0 : (__expf(m0) - 1.f);                                      \
        m1 = (m1 > 0.f) ? m1 : (__expf(m1) - 1.f);                                      \
        m2 = (m2 > 0.f) ? m2 : (__expf(m2) - 1.f);                                      \
        m3 = (m3 > 0.f) ? m3 : (__expf(m3) - 1.f);                                      \
        u32x2 hw;                                                                       \
        hw[0] = cvtpk(m0, m1);                                                          \
        hw[1] = cvtpk(m2, m3);                                                          \
        *(u32x2*)&h_lds[(w << 2) + J][lane << 2] = hw;                                  \
        a0 = a1 = a2 = a3 = 0.f;                                                        \
    }

#define WAIT4 asm volatile("s_waitcnt vmcnt(4)" ::: "memory"); __builtin_amdgcn_sched_barrier(0);

    float a0 = 0.f, a1 = 0.f, a2 = 0.f, a3 = 0.f;
    int gb = 0;

    // chunk stream: issue chunk k into buf k&1; after issuing k, wait(4) -> k-1 landed;
    // consume k-1 from buf (k&1)^1. Node boundary: next node's chunk 0 is the issue that
    // flushes the previous node's last chunk, then its epilogue runs in-stream.
    AGGF_ISSUE(elv0, 0, 0); ++gb;
    for (int c = 1; c < nch0; ++c) {
        int b = gb & 1; AGGF_ISSUE(elv0, c, b); ++gb; WAIT4; AGGF_CONS(b ^ 1);
    }
    { int b = gb & 1; AGGF_ISSUE(elv1, 0, b); ++gb; WAIT4; AGGF_CONS(b ^ 1); AGGF_EPI(0); }
    for (int c = 1; c < nch1; ++c) {
        int b = gb & 1; AGGF_ISSUE(elv1, c, b); ++gb; WAIT4; AGGF_CONS(b ^ 1);
    }
    { int b = gb & 1; AGGF_ISSUE(elv2, 0, b); ++gb; WAIT4; AGGF_CONS(b ^ 1); AGGF_EPI(1); }
    for (int c = 1; c < nch2; ++c) {
        int b = gb & 1; AGGF_ISSUE(elv2, c, b); ++gb; WAIT4; AGGF_CONS(b ^ 1);
    }
    { int b = gb & 1; AGGF_ISSUE(elv3, 0, b); ++gb; WAIT4; AGGF_CONS(b ^ 1); AGGF_EPI(2); }
    for (int c = 1; c < nch3; ++c) {
        int b = gb & 1; AGGF_ISSUE(elv3, c, b); ++gb; WAIT4; AGGF_CONS(b ^ 1);
    }
    asm volatile("s_waitcnt vmcnt(0)" ::: "memory");
    __builtin_amdgcn_sched_barrier(0);
    { int b = (gb & 1) ^ 1; AGGF_CONS(b); AGGF_EPI(3); }

    __syncthreads();

    // fused gemm2: t2[16 nodes][64] = h[16][256] @ Bt2[64][256]^T ; wave w owns 16 cols
    {
        const int l15 = lane & 15, quad = lane >> 4;
        f32x4 acc = (f32x4){0.f, 0.f, 0.f, 0.f};
#pragma unroll
        for (int st = 0; st < 8; ++st) {
            short8 afr = *(const short8*)&h_lds[l15][st * 32 + quad * 8];
            short8 bfr = *(const short8*)(Bt2 + (size_t)(w * 16 + l15) * 256 + st * 32 + quad * 8);
            acc = __builtin_amdgcn_mfma_f32_16x16x32_bf16(afr, bfr, acc, 0, 0, 0);
        }
#pragma unroll
        for (int r = 0; r < 4; ++r)
            t2[(size_t)(s0b + quad * 4 + r) * 64 + w * 16 + l15] = f2bf1(acc[r]);
    }
}

// ---------------- agg2: full-row contiguous DMA gather over t2 (128B rows), R8 form ----------------

__global__ __launch_bounds__(256) void agg2_kernel(const unsigned short* __restrict__ t2,
                                                   const int* __restrict__ deg,
                                                   const unsigned short* __restrict__ sdst,
                                                   float* __restrict__ out) {
    __shared__ __align__(16) unsigned int ring[4][2][256];    // 4 waves x 2 bufs x 1KB = 8KB

    const int w    = __builtin_amdgcn_readfirstlane(threadIdx.x >> 6);
    const int lane = threadIdx.x & 63;
    const int s0   = blockIdx.x * 16 + w * 4;
    const unsigned int* tb32 = (const unsigned int*)t2;
    const unsigned int loff = ((unsigned)(lane & 7)) << 2;    // 16B chunk within a 128B row

    const int end0 = deg[s0 + 0], end1 = deg[s0 + 1], end2 = deg[s0 + 2], end3 = deg[s0 + 3];
    const int elv0 = sdst[(size_t)(s0 + 0) * SLOT + lane];
    const int elv1 = sdst[(size_t)(s0 + 1) * SLOT + lane];
    const int elv2 = sdst[(size_t)(s0 + 2) * SLOT + lane];
    const int elv3 = sdst[(size_t)(s0 + 3) * SLOT + lane];
    asm volatile("" :: "v"(end0), "v"(end1), "v"(end2), "v"(end3),
                       "v"(elv0), "v"(elv1), "v"(elv2), "v"(elv3));

#define AGG2_ISSUE(ELV, D, B)                                                           \
    {                                                                                   \
        int r = __shfl(ELV, ((D) << 3) + (lane >> 3));                                  \
        glds16(tb32 + (unsigned)r * 32u + loff, &ring[w][B][0]);                        \
    }

#define AGG2_CONSUME(B)                                                                 \
    {                                                                                   \
        const unsigned int* rbp = &ring[w][B][lane & 31];                               \
        _Pragma("unroll")                                                               \
        for (int i = 0; i < 4; ++i) {                                                   \
            unsigned int v = rbp[(((i << 1) + (lane >> 5)) << 5)];                      \
            a0 += uasf(v << 16); a1 += uasf(v & 0xffff0000u);                           \
        }                                                                               \
    }

#define AGG2_NODE(J)                                                                    \
    {                                                                                   \
        const int end = end##J;                                                         \
        const int nch = ((end + 7) & ~7) >> 3;                                          \
        float a0 = 0.f, a1 = 0.f;                                                       \
        if (nch > 0) {                                                                  \
            AGG2_ISSUE(elv##J, 0, 0);                                                   \
            for (int d = 1; d < nch; ++d) {                                             \
                AGG2_ISSUE(elv##J, d, d & 1);                                           \
                asm volatile("s_waitcnt vmcnt(1)" ::: "memory");                        \
                __builtin_amdgcn_sched_barrier(0);                                      \
                AGG2_CONSUME((d - 1) & 1);                                              \
            }                                                                           \
            asm volatile("s_waitcnt vmcnt(0)" ::: "memory");                            \
            __builtin_amdgcn_sched_barrier(0);                                          \
            AGG2_CONSUME((nch - 1) & 1);                                                \
        }                                                                               \
        a0 += __shfl_xor(a0, 32);                                                       \
        a1 += __shfl_xor(a1, 32);                                                       \
        if (lane < 32) {                                                                \
            float iv = (end > 0) ? (1.0f / (float)end) : 0.f;                           \
            f32x2 rr; rr.x = a0 * iv; rr.y = a1 * iv;                                   \
            *(f32x2*)(out + (size_t)(s0 + J) * D_OUT + (lane & 31) * 2) = rr;           \
        }                                                                               \
    }

    AGG2_NODE(0);
    AGG2_NODE(1);
    AGG2_NODE(2);
    AGG2_NODE(3);
}

// ---------------- launch ----------------

extern "C" void kernel_launch(void* const* d_in, const int* in_sizes, int n_in,
                              void* d_out, int out_size, void* d_ws, size_t ws_size,
                              hipStream_t stream) {
    const float* X  = (const float*)d_in[0];
    const int*   ei = (const int*)d_in[1];
    const float* W1 = (const float*)d_in[2];
    const float* W2 = (const float*)d_in[3];
    const int* src = ei;             // edge_index[0] = segment ids
    const int* dst = ei + N_EDGES;   // edge_index[1] = gathered neighbors

    char* ws = (char*)d_ws;
    size_t off = 0;
    auto alloc = [&](size_t bytes) {
        off = (off + 255) & ~(size_t)255;
        void* p = ws + off;
        off += bytes;
        return p;
    };
    int*          gcnt = (int*)alloc((size_t)NBUK * 4);
    unsigned int* gbuk = (unsigned int*)alloc((size_t)NBUK * MAXB * 4);
    unsigned short* sdst = (unsigned short*)alloc(((size_t)N_NODES * SLOT + 64) * 2);
    int*          deg  = (int*)alloc((size_t)N_NODES * 4);
    unsigned short* Bt1 = (unsigned short*)alloc((size_t)D_H1 * D_IN * 2);
    unsigned short* Bt2 = (unsigned short*)alloc((size_t)D_OUT * D_H1 * 2);
    unsigned short* t1  = (unsigned short*)alloc((size_t)NR * D_H1 * 2);
    unsigned short* t2  = (unsigned short*)alloc((size_t)NR * D_OUT * 2);

    hipMemsetAsync(gcnt, 0, (size_t)NBUK * 4, stream);

    part_kernel<<<NPB, 256, 0, stream>>>(src, dst, gcnt, gbuk);
    sort_kernel<<<NBUK, 256, 0, stream>>>(gcnt, gbuk, sdst, deg);
    convw_kernel<<<(4 * 512 * 64 + 256 * 64 + 256 + 64 + 255) / 256, 256, 0, stream>>>(
        W1, W2, Bt1, Bt2, t1, t2);

    gemm1_kernel<<<(N_NODES + 127) / 128, 512, 0, stream>>>(X, Bt1, t1);
    aggf_kernel<<<N_NODES / 16, 256, 0, stream>>>(t1, deg, sdst, Bt2, t2);
    agg2_kernel<<<N_NODES / 16, 256, 0, stream>>>(t2, deg, sdst, (float*)d_out);
}

// Round 11
// 337.068 us; speedup vs baseline: 1.1103x; 1.0437x over previous
//
#include <hip/hip_runtime.h>
#include <hip/hip_bf16.h>
#include <stdint.h>

#define N_NODES 50000
#define N_EDGES 1600000
#define D_IN    512
#define D_H1    256   // 4 heads * 64 concat
#define D_OUT   64

#define NBUK    196   // coarse buckets: src>>8 (256 nodes each)
#define MAXB    9216  // per-bucket region capacity (mean 8163, +11 sigma)
#define EPB     4096  // edges per partition block
#define NPB     391   // ceil(N_EDGES / EPB)
#define SLOT    96    // per-node list stride (max degree ~58, list padded to mult-8)

#define NR      50001 // rows incl. zero row
#define ZROW    50000 // reserved all-zero row index (pad target)

#define NCONVW  578   // ceil((4*512*64 + 256*64 + 256 + 64) / 256)
#define NGEMM1  782   // ceil(N_NODES / 64)

typedef __attribute__((ext_vector_type(8))) short  short8;   // 8 bf16 = 4 VGPRs (MFMA A/B frag)
typedef __attribute__((ext_vector_type(4))) float  f32x4;    // MFMA C/D frag
typedef __attribute__((ext_vector_type(2))) float  f32x2;
typedef __attribute__((ext_vector_type(4))) unsigned int u32x4;
typedef __attribute__((ext_vector_type(2))) unsigned int u32x2;

// address-space-qualified void for the global_load_lds builtin
typedef __attribute__((address_space(1))) void GASV;
typedef __attribute__((address_space(3))) void LASV;

static __device__ __forceinline__ unsigned short f2bf(float f) {
    union { float f; unsigned int u; } c; c.f = f;
    unsigned int u = c.u;
    return (unsigned short)((u + 0x7FFFu + ((u >> 16) & 1u)) >> 16);  // RNE
}
// HW packed convert: dst.lo = bf16(a), dst.hi = bf16(b) — 1 op replaces 6.
static __device__ __forceinline__ unsigned int cvtpk(float a, float b) {
    unsigned int r;
    asm("v_cvt_pk_bf16_f32 %0, %1, %2" : "=v"(r) : "v"(a), "v"(b));
    return r;
}
static __device__ __forceinline__ unsigned short f2bf1(float f) {
    return (unsigned short)cvtpk(f, f);
}
static __device__ __forceinline__ float uasf(unsigned int u) {
    union { unsigned int u; float f; } c; c.u = u; return c.f;
}
static __device__ __forceinline__ void glds16(const unsigned int* g, unsigned int* l) {
    __builtin_amdgcn_global_load_lds((GASV*)g, (LASV*)l, 16, 0, 0);
}

// ---------------- launch 2: fused part (blocks 0..NPB-1) + convw (blocks NPB..) ----------------
// part: partition edges into 196 coarse buckets. convw: weight repack + zero-row init.
// Independent inputs -> merged grid overlaps them (graph capture forbids multi-stream).

__global__ __launch_bounds__(256) void pc_kernel(const int* __restrict__ src,
                                                 const int* __restrict__ dst,
                                                 int* __restrict__ gcnt,
                                                 unsigned int* __restrict__ gbuk,
                                                 const float* __restrict__ W1,
                                                 const float* __restrict__ W2,
                                                 unsigned short* __restrict__ Bt1,
                                                 unsigned short* __restrict__ Bt2,
                                                 unsigned short* __restrict__ t1,
                                                 unsigned short* __restrict__ t2) {
    __shared__ int hist[NBUK];
    __shared__ int lofs[NBUK];
    __shared__ int gbase[NBUK];
    __shared__ int sbuf[256];
    __shared__ unsigned int sorted[EPB];
    __shared__ unsigned char bid[EPB];

    const int t = threadIdx.x;

    if (blockIdx.x >= NPB) {
        // ---- convw ----
        int i = (blockIdx.x - NPB) * 256 + t;
        if (i < 4 * 512 * 64) {                 // W1[h][k][j] -> Bt1[(h*64+j)][k]
            int h = i >> 15;
            int k = (i >> 6) & 511;
            int j = i & 63;
            Bt1[(h * 64 + j) * 512 + k] = f2bf(W1[i]);
        } else if (i < 4 * 512 * 64 + 256 * 64) {
            int r = i - 4 * 512 * 64;           // W2[k][n] -> Bt2[n][k]
            int k = r >> 6;
            int n = r & 63;
            Bt2[n * 256 + k] = f2bf(W2[r]);
        } else {
            int r = i - (4 * 512 * 64 + 256 * 64);
            if (r < 256) {                      // zero row of t1
                t1[(size_t)ZROW * 256 + r] = 0;
            } else if (r < 256 + 64) {          // zero row of t2
                t2[(size_t)ZROW * 64 + (r - 256)] = 0;
            }
        }
        return;
    }

    // ---- part ----
    const int e0 = blockIdx.x * EPB;
    int ec = N_EDGES - e0; if (ec > EPB) ec = EPB;

    for (int i = t; i < NBUK; i += 256) hist[i] = 0;
    __syncthreads();

    unsigned int rec[16];
    int bb[16], idx[16];
#pragma unroll
    for (int j = 0; j < 16; ++j) {
        int i = j * 256 + t;
        if (i < ec) {
            int s = src[e0 + i], d = dst[e0 + i];
            int b = s >> 8;
            rec[j] = ((unsigned int)(s & 255) << 16) | (unsigned int)d;
            bb[j]  = b;
            idx[j] = atomicAdd(&hist[b], 1);
        } else bb[j] = -1;
    }
    __syncthreads();

    int v = (t < NBUK) ? hist[t] : 0;
    sbuf[t] = v;
    __syncthreads();
#pragma unroll
    for (int off = 1; off < 256; off <<= 1) {
        int x = (t >= off) ? sbuf[t - off] : 0;
        __syncthreads();
        sbuf[t] += x;
        __syncthreads();
    }
    if (t < NBUK) {
        lofs[t]  = sbuf[t] - v;
        gbase[t] = atomicAdd(&gcnt[t], v);
    }
    __syncthreads();

#pragma unroll
    for (int j = 0; j < 16; ++j) {
        if (bb[j] >= 0) {
            int p = lofs[bb[j]] + idx[j];
            sorted[p] = rec[j];
            bid[p] = (unsigned char)bb[j];
        }
    }
    __syncthreads();

    for (int i = t; i < ec; i += 256) {
        int b = bid[i];
        int p = gbase[b] + (i - lofs[b]);
        gbuk[(size_t)b * MAXB + p] = sorted[i];
    }
}

// ---------------- launch 3: fused sort (blocks 0..NBUK-1) + gemm1 (blocks NBUK..) ----------------
// sort needs part's output (prev launch); gemm1 needs convw's output (prev launch);
// they're independent of each other -> overlap. gemm1 refactored to 256-thread BM=64
// (4 waves, 1x4, wave tile 64x64) so both halves share one block shape.
// Shared memory is a 25.6KB union: sort uses 21.5KB, gemm1 25.6KB.

static __device__ __forceinline__ void sort_body(char* smem,
                                                 const int* __restrict__ gcnt,
                                                 const unsigned int* __restrict__ gbuk,
                                                 unsigned short* __restrict__ sdst,
                                                 int* __restrict__ deg) {
    int* hist = (int*)smem;                       // 1KB
    int* nofs = hist + 256;                       // 1KB
    int* sbuf = nofs + 256;                       // 1KB
    unsigned short* list = (unsigned short*)(sbuf + 256);   // 18KB

    const int t = threadIdx.x;
    const int b = blockIdx.x;
    const int cnt = gcnt[b];
    const unsigned int* buk = gbuk + (size_t)b * MAXB;

    hist[t] = 0;
    __syncthreads();
    for (int i = t; i < cnt; i += 256)
        atomicAdd(&hist[buk[i] >> 16], 1);
    __syncthreads();

    int v = hist[t];
    sbuf[t] = v;
    __syncthreads();
#pragma unroll
    for (int off = 1; off < 256; off <<= 1) {
        int x = (t >= off) ? sbuf[t - off] : 0;
        __syncthreads();
        sbuf[t] += x;
        __syncthreads();
    }
    nofs[t] = sbuf[t] - v;
    const int n = b * 256 + t;
    if (n < N_NODES) deg[n] = v;
    __syncthreads();

    for (int i = t; i < cnt; i += 256) {
        unsigned int r = buk[i];
        int p = atomicAdd(&nofs[r >> 16], 1);
        list[p] = (unsigned short)(r & 0xffffu);
    }
    __syncthreads();

    // cooperative coalesced writeout: 8 lanes per node, pad to mult-8 with ZROW
    // (deg==0 nodes get a full 8-entry ZROW list so downstream pipelines stay uniform)
    for (int base = 0; base < 256; base += 32) {
        int node = base + (t >> 3);
        int l8   = t & 7;
        int vv   = hist[node];
        int beg  = nofs[node] - vv;
        int n2   = b * 256 + node;
        if (n2 < N_NODES) {
            int words = ((vv + 7) & ~7) >> 1;
            if (words == 0) words = 4;
            unsigned int* out32 = (unsigned int*)(sdst + (size_t)n2 * SLOT);
            for (int j2 = l8; j2 < words; j2 += 8) {
                unsigned int lo = (2 * j2     < vv) ? list[beg + 2 * j2]     : (unsigned int)ZROW;
                unsigned int hi = (2 * j2 + 1 < vv) ? list[beg + 2 * j2 + 1] : (unsigned int)ZROW;
                out32[j2] = lo | (hi << 16);
            }
        }
    }
}

static __device__ __forceinline__ void gemm1_body(char* smem, int bm,
                                                  const float* __restrict__ A,
                                                  const unsigned short* __restrict__ Bt,
                                                  unsigned short* __restrict__ C) {
    constexpr int BM = 64, BK = 32, LDK = 40, K = D_IN, M = N_NODES;
    unsigned short* As = (unsigned short*)smem;    // 64*40*2  = 5.0 KB
    unsigned short* Bs = As + BM * LDK;            // 256*40*2 = 20.0 KB

    const int tid  = threadIdx.x;
    const int lane = tid & 63;
    const int w    = tid >> 6;      // 4 waves, 1x4: wave w owns cols w*64..w*64+63
    const int wn   = w * 64;
    const int quad = lane >> 4;
    const int l15  = lane & 15;

    f32x4 acc[4][4];
#pragma unroll
    for (int mi = 0; mi < 4; ++mi)
#pragma unroll
        for (int ni = 0; ni < 4; ++ni)
            acc[mi][ni] = (f32x4){0.f, 0.f, 0.f, 0.f};

    const int r0 = tid >> 2;      // 0..63
    const int f8 = tid & 3;       // 8-elem chunk within a 32-col row

    for (int k0 = 0; k0 < K; k0 += BK) {
        {   // stage A (64 x 32 fp32 -> bf16), 8 floats per thread, HW pack-convert
            int grow = bm * BM + r0;
            if (grow >= M) grow = M - 1;
            const float* ap = A + (size_t)grow * K + k0 + f8 * 8;
            f32x4 v0 = *(const f32x4*)ap;
            f32x4 v1 = *(const f32x4*)(ap + 4);
            u32x4 pk;
            pk[0] = cvtpk(v0[0], v0[1]);
            pk[1] = cvtpk(v0[2], v0[3]);
            pk[2] = cvtpk(v1[0], v1[1]);
            pk[3] = cvtpk(v1[2], v1[3]);
            *(u32x4*)&As[r0 * LDK + f8 * 8] = pk;
        }
        {   // stage B (256 x 32 bf16), four u32x4 per thread
#pragma unroll
            for (int p = 0; p < 4; ++p) {
                int row = p * 64 + r0;
                u32x4 v = *(const u32x4*)(Bt + (size_t)row * K + k0 + f8 * 8);
                *(u32x4*)&Bs[row * LDK + f8 * 8] = v;
            }
        }
        __syncthreads();

        short8 af[4], bfr[4];
#pragma unroll
        for (int mi = 0; mi < 4; ++mi)
            af[mi] = *(const short8*)&As[(mi * 16 + l15) * LDK + quad * 8];
#pragma unroll
        for (int ni = 0; ni < 4; ++ni)
            bfr[ni] = *(const short8*)&Bs[(wn + ni * 16 + l15) * LDK + quad * 8];
#pragma unroll
        for (int mi = 0; mi < 4; ++mi)
#pragma unroll
            for (int ni = 0; ni < 4; ++ni)
                acc[mi][ni] = __builtin_amdgcn_mfma_f32_16x16x32_bf16(af[mi], bfr[ni], acc[mi][ni], 0, 0, 0);
        __syncthreads();
    }

#pragma unroll
    for (int mi = 0; mi < 4; ++mi) {
        int row0 = bm * BM + mi * 16 + quad * 4;
#pragma unroll
        for (int ni = 0; ni < 4; ++ni) {
            int col = wn + ni * 16 + l15;
#pragma unroll
            for (int r = 0; r < 4; ++r) {
                int row = row0 + r;
                if (row < M) C[(size_t)row * 256 + col] = f2bf1(acc[mi][ni][r]);
            }
        }
    }
}

__global__ __launch_bounds__(256) void sg_kernel(const int* __restrict__ gcnt,
                                                 const unsigned int* __restrict__ gbuk,
                                                 unsigned short* __restrict__ sdst,
                                                 int* __restrict__ deg,
                                                 const float* __restrict__ A,
                                                 const unsigned short* __restrict__ Bt,
                                                 unsigned short* __restrict__ C) {
    __shared__ __align__(16) char smem[25600];
    if (blockIdx.x < NBUK) sort_body(smem, gcnt, gbuk, sdst, deg);
    else                   gemm1_body(smem, blockIdx.x - NBUK, A, Bt, C);
}

// ---------------- aggF: fused agg1 + gemm2, continuous cross-node DMA pipeline ----------------
// At the ~9 TB/s gather-service wall (R8/R10: 8.3-8.4 TB/s on 909 MB). Unchanged from R10.

__global__ __launch_bounds__(256) void aggf_kernel(const unsigned short* __restrict__ t1,
                                                   const int* __restrict__ deg,
                                                   const unsigned short* __restrict__ sdst,
                                                   const unsigned short* __restrict__ Bt2,
                                                   unsigned short* __restrict__ t2) {
    __shared__ __align__(16) unsigned int ring[4][2][1024];   // 4 waves x 2 bufs x 4KB = 32KB
    __shared__ __align__(16) unsigned short h_lds[16][264];   // 528B rows (bank-spread), 8.25KB

    const int w    = __builtin_amdgcn_readfirstlane(threadIdx.x >> 6);
    const int lane = threadIdx.x & 63;
    const int s0b  = blockIdx.x * 16;
    const int s0   = s0b + w * 4;
    const unsigned int* tb32 = (const unsigned int*)t1;
    const unsigned int loff = ((unsigned)(lane & 31)) << 2;   // 16B chunk within a 512B row

    const int end0 = deg[s0 + 0], end1 = deg[s0 + 1], end2 = deg[s0 + 2], end3 = deg[s0 + 3];
    const int elv0 = sdst[(size_t)(s0 + 0) * SLOT + lane];
    const int elv1 = sdst[(size_t)(s0 + 1) * SLOT + lane];
    const int elv2 = sdst[(size_t)(s0 + 2) * SLOT + lane];
    const int elv3 = sdst[(size_t)(s0 + 3) * SLOT + lane];
    asm volatile("" :: "v"(end0), "v"(end1), "v"(end2), "v"(end3),
                       "v"(elv0), "v"(elv1), "v"(elv2), "v"(elv3));

    const int nch0 = end0 ? (end0 + 7) >> 3 : 1;   // uniform pad8 chunks, >= 1
    const int nch1 = end1 ? (end1 + 7) >> 3 : 1;
    const int nch2 = end2 ? (end2 + 7) >> 3 : 1;
    const int nch3 = end3 ? (end3 + 7) >> 3 : 1;

#define AGGF_ISSUE(ELV, C, B)                                                           \
    {                                                                                   \
        int q  = ((C) << 3) + (lane >> 5);                                              \
        int ra = __shfl(ELV, q);                                                        \
        int rb_ = __shfl(ELV, q + 2);                                                   \
        int rc = __shfl(ELV, q + 4);                                                    \
        int rd = __shfl(ELV, q + 6);                                                    \
        unsigned int* dp = &ring[w][B][0];                                              \
        glds16(tb32 + (unsigned)ra  * 128u + loff, dp);                                 \
        glds16(tb32 + (unsigned)rb_ * 128u + loff, dp + 256);                           \
        glds16(tb32 + (unsigned)rc  * 128u + loff, dp + 512);                           \
        glds16(tb32 + (unsigned)rd  * 128u + loff, dp + 768);                           \
    }

#define AGGF_CONS(B)                                                                    \
    {                                                                                   \
        const unsigned int* rbp = &ring[w][B][lane << 1];                               \
        _Pragma("unroll")                                                               \
        for (int r = 0; r < 8; ++r) {                                                   \
            u32x2 v = *(const u32x2*)(rbp + (r << 7));                                  \
            a0 += uasf(v[0] << 16); a1 += uasf(v[0] & 0xffff0000u);                     \
            a2 += uasf(v[1] << 16); a3 += uasf(v[1] & 0xffff0000u);                     \
        }                                                                               \
    }

#define AGGF_EPI(J)                                                                     \
    {                                                                                   \
        float iv = (end##J > 0) ? (1.0f / (float)end##J) : 0.f;                         \
        float m0 = a0 * iv, m1 = a1 * iv, m2 = a2 * iv, m3 = a3 * iv;                   \
        m0 = (m0 > 0.f) ? m0 : (__expf(m0) - 1.f);                                      \
        m1 = (m1 > 0.f) ? m1 : (__expf(m1) - 1.f);                                      \
        m2 = (m2 > 0.f) ? m2 : (__expf(m2) - 1.f);                                      \
        m3 = (m3 > 0.f) ? m3 : (__expf(m3) - 1.f);                                      \
        u32x2 hw;                                                                       \
        hw[0] = cvtpk(m0, m1);                                                          \
        hw[1] = cvtpk(m2, m3);                                                          \
        *(u32x2*)&h_lds[(w << 2) + J][lane << 2] = hw;                                  \
        a0 = a1 = a2 = a3 = 0.f;                                                        \
    }

#define WAIT4 asm volatile("s_waitcnt vmcnt(4)" ::: "memory"); __builtin_amdgcn_sched_barrier(0);

    float a0 = 0.f, a1 = 0.f, a2 = 0.f, a3 = 0.f;
    int gb = 0;

    AGGF_ISSUE(elv0, 0, 0); ++gb;
    for (int c = 1; c < nch0; ++c) {
        int b = gb & 1; AGGF_ISSUE(elv0, c, b); ++gb; WAIT4; AGGF_CONS(b ^ 1);
    }
    { int b = gb & 1; AGGF_ISSUE(elv1, 0, b); ++gb; WAIT4; AGGF_CONS(b ^ 1); AGGF_EPI(0); }
    for (int c = 1; c < nch1; ++c) {
        int b = gb & 1; AGGF_ISSUE(elv1, c, b); ++gb; WAIT4; AGGF_CONS(b ^ 1);
    }
    { int b = gb & 1; AGGF_ISSUE(elv2, 0, b); ++gb; WAIT4; AGGF_CONS(b ^ 1); AGGF_EPI(1); }
    for (int c = 1; c < nch2; ++c) {
        int b = gb & 1; AGGF_ISSUE(elv2, c, b); ++gb; WAIT4; AGGF_CONS(b ^ 1);
    }
    { int b = gb & 1; AGGF_ISSUE(elv3, 0, b); ++gb; WAIT4; AGGF_CONS(b ^ 1); AGGF_EPI(2); }
    for (int c = 1; c < nch3; ++c) {
        int b = gb & 1; AGGF_ISSUE(elv3, c, b); ++gb; WAIT4; AGGF_CONS(b ^ 1);
    }
    asm volatile("s_waitcnt vmcnt(0)" ::: "memory");
    __builtin_amdgcn_sched_barrier(0);
    { int b = (gb & 1) ^ 1; AGGF_CONS(b); AGGF_EPI(3); }

    __syncthreads();

    // fused gemm2: t2[16 nodes][64] = h[16][256] @ Bt2[64][256]^T ; wave w owns 16 cols
    {
        const int l15 = lane & 15, quad = lane >> 4;
        f32x4 acc = (f32x4){0.f, 0.f, 0.f, 0.f};
#pragma unroll
        for (int st = 0; st < 8; ++st) {
            short8 afr = *(const short8*)&h_lds[l15][st * 32 + quad * 8];
            short8 bfr = *(const short8*)(Bt2 + (size_t)(w * 16 + l15) * 256 + st * 32 + quad * 8);
            acc = __builtin_amdgcn_mfma_f32_16x16x32_bf16(afr, bfr, acc, 0, 0, 0);
        }
#pragma unroll
        for (int r = 0; r < 4; ++r)
            t2[(size_t)(s0b + quad * 4 + r) * 64 + w * 16 + l15] = f2bf1(acc[r]);
    }
}

// ---------------- agg2: full-row contiguous DMA gather over t2 (128B rows), R8 form ----------------

__global__ __launch_bounds__(256) void agg2_kernel(const unsigned short* __restrict__ t2,
                                                   const int* __restrict__ deg,
                                                   const unsigned short* __restrict__ sdst,
                                                   float* __restrict__ out) {
    __shared__ __align__(16) unsigned int ring[4][2][256];    // 4 waves x 2 bufs x 1KB = 8KB

    const int w    = __builtin_amdgcn_readfirstlane(threadIdx.x >> 6);
    const int lane = threadIdx.x & 63;
    const int s0   = blockIdx.x * 16 + w * 4;
    const unsigned int* tb32 = (const unsigned int*)t2;
    const unsigned int loff = ((unsigned)(lane & 7)) << 2;    // 16B chunk within a 128B row

    const int end0 = deg[s0 + 0], end1 = deg[s0 + 1], end2 = deg[s0 + 2], end3 = deg[s0 + 3];
    const int elv0 = sdst[(size_t)(s0 + 0) * SLOT + lane];
    const int elv1 = sdst[(size_t)(s0 + 1) * SLOT + lane];
    const int elv2 = sdst[(size_t)(s0 + 2) * SLOT + lane];
    const int elv3 = sdst[(size_t)(s0 + 3) * SLOT + lane];
    asm volatile("" :: "v"(end0), "v"(end1), "v"(end2), "v"(end3),
                       "v"(elv0), "v"(elv1), "v"(elv2), "v"(elv3));

#define AGG2_ISSUE(ELV, D, B)                                                           \
    {                                                                                   \
        int r = __shfl(ELV, ((D) << 3) + (lane >> 3));                                  \
        glds16(tb32 + (unsigned)r * 32u + loff, &ring[w][B][0]);                        \
    }

#define AGG2_CONSUME(B)                                                                 \
    {                                                                                   \
        const unsigned int* rbp = &ring[w][B][lane & 31];                               \
        _Pragma("unroll")                                                               \
        for (int i = 0; i < 4; ++i) {                                                   \
            unsigned int v = rbp[(((i << 1) + (lane >> 5)) << 5)];                      \
            a0 += uasf(v << 16); a1 += uasf(v & 0xffff0000u);                           \
        }                                                                               \
    }

#define AGG2_NODE(J)                                                                    \
    {                                                                                   \
        const int end = end##J;                                                         \
        const int nch = ((end + 7) & ~7) >> 3;                                          \
        float a0 = 0.f, a1 = 0.f;                                                       \
        if (nch > 0) {                                                                  \
            AGG2_ISSUE(elv##J, 0, 0);                                                   \
            for (int d = 1; d < nch; ++d) {                                             \
                AGG2_ISSUE(elv##J, d, d & 1);                                           \
                asm volatile("s_waitcnt vmcnt(1)" ::: "memory");                        \
                __builtin_amdgcn_sched_barrier(0);                                      \
                AGG2_CONSUME((d - 1) & 1);                                              \
            }                                                                           \
            asm volatile("s_waitcnt vmcnt(0)" ::: "memory");                            \
            __builtin_amdgcn_sched_barrier(0);                                          \
            AGG2_CONSUME((nch - 1) & 1);                                                \
        }                                                                               \
        a0 += __shfl_xor(a0, 32);                                                       \
        a1 += __shfl_xor(a1, 32);                                                       \
        if (lane < 32) {                                                                \
            float iv = (end > 0) ? (1.0f / (float)end) : 0.f;                           \
            f32x2 rr; rr.x = a0 * iv; rr.y = a1 * iv;                                   \
            *(f32x2*)(out + (size_t)(s0 + J) * D_OUT + (lane & 31) * 2) = rr;           \
        }                                                                               \
    }

    AGG2_NODE(0);
    AGG2_NODE(1);
    AGG2_NODE(2);
    AGG2_NODE(3);
}

// ---------------- launch ----------------

extern "C" void kernel_launch(void* const* d_in, const int* in_sizes, int n_in,
                              void* d_out, int out_size, void* d_ws, size_t ws_size,
                              hipStream_t stream) {
    const float* X  = (const float*)d_in[0];
    const int*   ei = (const int*)d_in[1];
    const float* W1 = (const float*)d_in[2];
    const float* W2 = (const float*)d_in[3];
    const int* src = ei;             // edge_index[0] = segment ids
    const int* dst = ei + N_EDGES;   // edge_index[1] = gathered neighbors

    char* ws = (char*)d_ws;
    size_t off = 0;
    auto alloc = [&](size_t bytes) {
        off = (off + 255) & ~(size_t)255;
        void* p = ws + off;
        off += bytes;
        return p;
    };
    int*          gcnt = (int*)alloc((size_t)NBUK * 4);
    unsigned int* gbuk = (unsigned int*)alloc((size_t)NBUK * MAXB * 4);
    unsigned short* sdst = (unsigned short*)alloc(((size_t)N_NODES * SLOT + 64) * 2);
    int*          deg  = (int*)alloc((size_t)N_NODES * 4);
    unsigned short* Bt1 = (unsigned short*)alloc((size_t)D_H1 * D_IN * 2);
    unsigned short* Bt2 = (unsigned short*)alloc((size_t)D_OUT * D_H1 * 2);
    unsigned short* t1  = (unsigned short*)alloc((size_t)NR * D_H1 * 2);
    unsigned short* t2  = (unsigned short*)alloc((size_t)NR * D_OUT * 2);

    hipMemsetAsync(gcnt, 0, (size_t)NBUK * 4, stream);

    pc_kernel<<<NPB + NCONVW, 256, 0, stream>>>(src, dst, gcnt, gbuk, W1, W2, Bt1, Bt2, t1, t2);
    sg_kernel<<<NBUK + NGEMM1, 256, 0, stream>>>(gcnt, gbuk, sdst, deg, X, Bt1, t1);
    aggf_kernel<<<N_NODES / 16, 256, 0, stream>>>(t1, deg, sdst, Bt2, t2);
    agg2_kernel<<<N_NODES / 16, 256, 0, stream>>>(t2, deg, sdst, (float*)d_out);
}

// Round 12
// 332.053 us; speedup vs baseline: 1.1270x; 1.0151x over previous
//
#include <hip/hip_runtime.h>
#include <hip/hip_bf16.h>
#include <stdint.h>

#define N_NODES 50000
#define N_EDGES 1600000
#define D_IN    512
#define D_H1    256   // 4 heads * 64 concat
#define D_OUT   64

#define NBUK    196   // coarse buckets: src>>8 (256 nodes each)
#define MAXB    9216  // per-bucket region capacity (mean 8163, +11 sigma)
#define EPB     4096  // edges per partition block
#define NPB     391   // ceil(N_EDGES / EPB)
#define SLOT    96    // per-node list stride (max degree ~58, list padded to mult-8)

#define NR      50001 // rows incl. zero row
#define ZROW    50000 // reserved all-zero row index (pad target)

#define NCONVW  578   // ceil((4*512*64 + 256*64 + 256 + 64) / 256)
#define NGEMM1  391   // ceil(N_NODES / 128)

typedef __attribute__((ext_vector_type(8))) short  short8;   // 8 bf16 = 4 VGPRs (MFMA A/B frag)
typedef __attribute__((ext_vector_type(4))) float  f32x4;    // MFMA C/D frag
typedef __attribute__((ext_vector_type(2))) float  f32x2;
typedef __attribute__((ext_vector_type(4))) unsigned int u32x4;
typedef __attribute__((ext_vector_type(2))) unsigned int u32x2;

// address-space-qualified void for the global_load_lds builtin
typedef __attribute__((address_space(1))) void GASV;
typedef __attribute__((address_space(3))) void LASV;

static __device__ __forceinline__ unsigned short f2bf(float f) {
    union { float f; unsigned int u; } c; c.f = f;
    unsigned int u = c.u;
    return (unsigned short)((u + 0x7FFFu + ((u >> 16) & 1u)) >> 16);  // RNE
}
// HW packed convert: dst.lo = bf16(a), dst.hi = bf16(b) — 1 op replaces 6.
static __device__ __forceinline__ unsigned int cvtpk(float a, float b) {
    unsigned int r;
    asm("v_cvt_pk_bf16_f32 %0, %1, %2" : "=v"(r) : "v"(a), "v"(b));
    return r;
}
static __device__ __forceinline__ unsigned short f2bf1(float f) {
    return (unsigned short)cvtpk(f, f);
}
static __device__ __forceinline__ float uasf(unsigned int u) {
    union { unsigned int u; float f; } c; c.u = u; return c.f;
}
static __device__ __forceinline__ void glds16(const unsigned int* g, unsigned int* l) {
    __builtin_amdgcn_global_load_lds((GASV*)g, (LASV*)l, 16, 0, 0);
}

// ---------------- launch 2: fused part (blocks 0..NPB-1) + convw (blocks NPB..) ----------------
// part: partition edges into 196 coarse buckets. convw: weight repack + zero-row init.
// Independent inputs -> merged grid overlaps them (graph capture forbids multi-stream).

__global__ __launch_bounds__(256) void pc_kernel(const int* __restrict__ src,
                                                 const int* __restrict__ dst,
                                                 int* __restrict__ gcnt,
                                                 unsigned int* __restrict__ gbuk,
                                                 const float* __restrict__ W1,
                                                 const float* __restrict__ W2,
                                                 unsigned short* __restrict__ Bt1,
                                                 unsigned short* __restrict__ Bt2,
                                                 unsigned short* __restrict__ t1,
                                                 unsigned short* __restrict__ t2) {
    __shared__ int hist[NBUK];
    __shared__ int lofs[NBUK];
    __shared__ int gbase[NBUK];
    __shared__ int sbuf[256];
    __shared__ unsigned int sorted[EPB];
    __shared__ unsigned char bid[EPB];

    const int t = threadIdx.x;

    if (blockIdx.x >= NPB) {
        // ---- convw ----
        int i = (blockIdx.x - NPB) * 256 + t;
        if (i < 4 * 512 * 64) {                 // W1[h][k][j] -> Bt1[(h*64+j)][k]
            int h = i >> 15;
            int k = (i >> 6) & 511;
            int j = i & 63;
            Bt1[(h * 64 + j) * 512 + k] = f2bf(W1[i]);
        } else if (i < 4 * 512 * 64 + 256 * 64) {
            int r = i - 4 * 512 * 64;           // W2[k][n] -> Bt2[n][k]
            int k = r >> 6;
            int n = r & 63;
            Bt2[n * 256 + k] = f2bf(W2[r]);
        } else {
            int r = i - (4 * 512 * 64 + 256 * 64);
            if (r < 256) {                      // zero row of t1
                t1[(size_t)ZROW * 256 + r] = 0;
            } else if (r < 256 + 64) {          // zero row of t2
                t2[(size_t)ZROW * 64 + (r - 256)] = 0;
            }
        }
        return;
    }

    // ---- part ----
    const int e0 = blockIdx.x * EPB;
    int ec = N_EDGES - e0; if (ec > EPB) ec = EPB;

    for (int i = t; i < NBUK; i += 256) hist[i] = 0;
    __syncthreads();

    unsigned int rec[16];
    int bb[16], idx[16];
#pragma unroll
    for (int j = 0; j < 16; ++j) {
        int i = j * 256 + t;
        if (i < ec) {
            int s = src[e0 + i], d = dst[e0 + i];
            int b = s >> 8;
            rec[j] = ((unsigned int)(s & 255) << 16) | (unsigned int)d;
            bb[j]  = b;
            idx[j] = atomicAdd(&hist[b], 1);
        } else bb[j] = -1;
    }
    __syncthreads();

    int v = (t < NBUK) ? hist[t] : 0;
    sbuf[t] = v;
    __syncthreads();
#pragma unroll
    for (int off = 1; off < 256; off <<= 1) {
        int x = (t >= off) ? sbuf[t - off] : 0;
        __syncthreads();
        sbuf[t] += x;
        __syncthreads();
    }
    if (t < NBUK) {
        lofs[t]  = sbuf[t] - v;
        gbase[t] = atomicAdd(&gcnt[t], v);
    }
    __syncthreads();

#pragma unroll
    for (int j = 0; j < 16; ++j) {
        if (bb[j] >= 0) {
            int p = lofs[bb[j]] + idx[j];
            sorted[p] = rec[j];
            bid[p] = (unsigned char)bb[j];
        }
    }
    __syncthreads();

    for (int i = t; i < ec; i += 256) {
        int b = bid[i];
        int p = gbase[b] + (i - lofs[b]);
        gbuk[(size_t)b * MAXB + p] = sorted[i];
    }
}

// ---------------- launch 3: fused sort (blocks 0..NBUK-1) + gemm1 (blocks NBUK..) ----------------
// 512-thread blocks this round: gemm1 restored to the proven R10 BM=128/8-wave form
// (2x better B-tile amortization vs R11's BM=64); sort adapted to 512 threads
// (2x histogram/scatter parallelism; scan on first 256 lanes; writeout 16 lanes/node).
// Shared memory union: gemm1 30.75KB, sort 21.5KB.

static __device__ __forceinline__ void sort_body(char* smem,
                                                 const int* __restrict__ gcnt,
                                                 const unsigned int* __restrict__ gbuk,
                                                 unsigned short* __restrict__ sdst,
                                                 int* __restrict__ deg) {
    int* hist = (int*)smem;                       // 1KB
    int* nofs = hist + 256;                       // 1KB
    int* sbuf = nofs + 256;                       // 1KB
    unsigned short* list = (unsigned short*)(sbuf + 256);   // 18KB

    const int t = threadIdx.x;                    // 0..511
    const int b = blockIdx.x;
    const int cnt = gcnt[b];
    const unsigned int* buk = gbuk + (size_t)b * MAXB;

    if (t < 256) hist[t] = 0;
    __syncthreads();
    for (int i = t; i < cnt; i += 512)
        atomicAdd(&hist[buk[i] >> 16], 1);
    __syncthreads();

    int v = (t < 256) ? hist[t] : 0;
    if (t < 256) sbuf[t] = v;
    __syncthreads();
#pragma unroll
    for (int off = 1; off < 256; off <<= 1) {
        int x = (t >= off && t < 256) ? sbuf[t - off] : 0;
        __syncthreads();
        if (t < 256) sbuf[t] += x;
        __syncthreads();
    }
    if (t < 256) {
        nofs[t] = sbuf[t] - v;
        const int n = b * 256 + t;
        if (n < N_NODES) deg[n] = v;
    }
    __syncthreads();

    for (int i = t; i < cnt; i += 512) {
        unsigned int r = buk[i];
        int p = atomicAdd(&nofs[r >> 16], 1);
        list[p] = (unsigned short)(r & 0xffffu);
    }
    __syncthreads();

    // cooperative coalesced writeout: 16 lanes per node, pad to mult-8 with ZROW
    // (deg==0 nodes get a full 8-entry ZROW list so downstream pipelines stay uniform)
    for (int base = 0; base < 256; base += 32) {
        int node = base + (t >> 4);
        int l16  = t & 15;
        int vv   = hist[node];
        int beg  = nofs[node] - vv;
        int n2   = b * 256 + node;
        if (n2 < N_NODES) {
            int words = ((vv + 7) & ~7) >> 1;
            if (words == 0) words = 4;
            unsigned int* out32 = (unsigned int*)(sdst + (size_t)n2 * SLOT);
            for (int j2 = l16; j2 < words; j2 += 16) {
                unsigned int lo = (2 * j2     < vv) ? list[beg + 2 * j2]     : (unsigned int)ZROW;
                unsigned int hi = (2 * j2 + 1 < vv) ? list[beg + 2 * j2 + 1] : (unsigned int)ZROW;
                out32[j2] = lo | (hi << 16);
            }
        }
    }
}

static __device__ __forceinline__ void gemm1_body(char* smem, int bm,
                                                  const float* __restrict__ A,
                                                  const unsigned short* __restrict__ Bt,
                                                  unsigned short* __restrict__ C) {
    constexpr int BM = 128, BK = 32, LDK = 40, K = D_IN, M = N_NODES;
    unsigned short* As = (unsigned short*)smem;    // 128*40*2 = 10.25 KB
    unsigned short* Bs = As + BM * LDK;            // 256*40*2 = 20.5 KB

    const int tid  = threadIdx.x;
    const int lane = tid & 63;
    const int w    = tid >> 6;
    const int wm   = (w >> 2) * 64;
    const int wn   = (w & 3) * 64;
    const int quad = lane >> 4;
    const int l15  = lane & 15;

    f32x4 acc[4][4];
#pragma unroll
    for (int mi = 0; mi < 4; ++mi)
#pragma unroll
        for (int ni = 0; ni < 4; ++ni)
            acc[mi][ni] = (f32x4){0.f, 0.f, 0.f, 0.f};

    const int r0 = tid >> 2;      // 0..127
    const int f8 = tid & 3;       // 8-elem chunk within a 32-col row

    for (int k0 = 0; k0 < K; k0 += BK) {
        {   // stage A (128 x 32 fp32 -> bf16), 8 floats per thread, HW pack-convert
            int grow = bm * BM + r0;
            if (grow >= M) grow = M - 1;
            const float* ap = A + (size_t)grow * K + k0 + f8 * 8;
            f32x4 v0 = *(const f32x4*)ap;
            f32x4 v1 = *(const f32x4*)(ap + 4);
            u32x4 pk;
            pk[0] = cvtpk(v0[0], v0[1]);
            pk[1] = cvtpk(v0[2], v0[3]);
            pk[2] = cvtpk(v1[0], v1[1]);
            pk[3] = cvtpk(v1[2], v1[3]);
            *(u32x4*)&As[r0 * LDK + f8 * 8] = pk;
        }
        {   // stage B (256 x 32 bf16), two u32x4 per thread
#pragma unroll
            for (int p = 0; p < 2; ++p) {
                int row = p * 128 + r0;
                u32x4 v = *(const u32x4*)(Bt + (size_t)row * K + k0 + f8 * 8);
                *(u32x4*)&Bs[row * LDK + f8 * 8] = v;
            }
        }
        __syncthreads();

        short8 af[4], bfr[4];
#pragma unroll
        for (int mi = 0; mi < 4; ++mi)
            af[mi] = *(const short8*)&As[(wm + mi * 16 + l15) * LDK + quad * 8];
#pragma unroll
        for (int ni = 0; ni < 4; ++ni)
            bfr[ni] = *(const short8*)&Bs[(wn + ni * 16 + l15) * LDK + quad * 8];
#pragma unroll
        for (int mi = 0; mi < 4; ++mi)
#pragma unroll
            for (int ni = 0; ni < 4; ++ni)
                acc[mi][ni] = __builtin_amdgcn_mfma_f32_16x16x32_bf16(af[mi], bfr[ni], acc[mi][ni], 0, 0, 0);
        __syncthreads();
    }

#pragma unroll
    for (int mi = 0; mi < 4; ++mi) {
        int row0 = bm * BM + wm + mi * 16 + quad * 4;
#pragma unroll
        for (int ni = 0; ni < 4; ++ni) {
            int col = wn + ni * 16 + l15;
#pragma unroll
            for (int r = 0; r < 4; ++r) {
                int row = row0 + r;
                if (row < M) C[(size_t)row * 256 + col] = f2bf1(acc[mi][ni][r]);
            }
        }
    }
}

__global__ __launch_bounds__(512) void sg_kernel(const int* __restrict__ gcnt,
                                                 const unsigned int* __restrict__ gbuk,
                                                 unsigned short* __restrict__ sdst,
                                                 int* __restrict__ deg,
                                                 const float* __restrict__ A,
                                                 const unsigned short* __restrict__ Bt,
                                                 unsigned short* __restrict__ C) {
    __shared__ __align__(16) char smem[30720];
    if (blockIdx.x < NBUK) sort_body(smem, gcnt, gbuk, sdst, deg);
    else                   gemm1_body(smem, blockIdx.x - NBUK, A, Bt, C);
}

// ---------------- aggF: fused agg1 + gemm2, continuous cross-node DMA pipeline ----------------
// At the ~14 B/cy/CU per-CU gather-service wall (R0/R4/R8/R10 all converge). Unchanged.

__global__ __launch_bounds__(256) void aggf_kernel(const unsigned short* __restrict__ t1,
                                                   const int* __restrict__ deg,
                                                   const unsigned short* __restrict__ sdst,
                                                   const unsigned short* __restrict__ Bt2,
                                                   unsigned short* __restrict__ t2) {
    __shared__ __align__(16) unsigned int ring[4][2][1024];   // 4 waves x 2 bufs x 4KB = 32KB
    __shared__ __align__(16) unsigned short h_lds[16][264];   // 528B rows (bank-spread), 8.25KB

    const int w    = __builtin_amdgcn_readfirstlane(threadIdx.x >> 6);
    const int lane = threadIdx.x & 63;
    const int s0b  = blockIdx.x * 16;
    const int s0   = s0b + w * 4;
    const unsigned int* tb32 = (const unsigned int*)t1;
    const unsigned int loff = ((unsigned)(lane & 31)) << 2;   // 16B chunk within a 512B row

    const int end0 = deg[s0 + 0], end1 = deg[s0 + 1], end2 = deg[s0 + 2], end3 = deg[s0 + 3];
    const int elv0 = sdst[(size_t)(s0 + 0) * SLOT + lane];
    const int elv1 = sdst[(size_t)(s0 + 1) * SLOT + lane];
    const int elv2 = sdst[(size_t)(s0 + 2) * SLOT + lane];
    const int elv3 = sdst[(size_t)(s0 + 3) * SLOT + lane];
    asm volatile("" :: "v"(end0), "v"(end1), "v"(end2), "v"(end3),
                       "v"(elv0), "v"(elv1), "v"(elv2), "v"(elv3));

    const int nch0 = end0 ? (end0 + 7) >> 3 : 1;   // uniform pad8 chunks, >= 1
    const int nch1 = end1 ? (end1 + 7) >> 3 : 1;
    const int nch2 = end2 ? (end2 + 7) >> 3 : 1;
    const int nch3 = end3 ? (end3 + 7) >> 3 : 1;

#define AGGF_ISSUE(ELV, C, B)                                                           \
    {                                                                                   \
        int q  = ((C) << 3) + (lane >> 5);                                              \
        int ra = __shfl(ELV, q);                                                        \
        int rb_ = __shfl(ELV, q + 2);                                                   \
        int rc = __shfl(ELV, q + 4);                                                    \
        int rd = __shfl(ELV, q + 6);                                                    \
        unsigned int* dp = &ring[w][B][0];                                              \
        glds16(tb32 + (unsigned)ra  * 128u + loff, dp);                                 \
        glds16(tb32 + (unsigned)rb_ * 128u + loff, dp + 256);                           \
        glds16(tb32 + (unsigned)rc  * 128u + loff, dp + 512);                           \
        glds16(tb32 + (unsigned)rd  * 128u + loff, dp + 768);                           \
    }

#define AGGF_CONS(B)                                                                    \
    {                                                                                   \
        const unsigned int* rbp = &ring[w][B][lane << 1];                               \
        _Pragma("unroll")                                                               \
        for (int r = 0; r < 8; ++r) {                                                   \
            u32x2 v = *(const u32x2*)(rbp + (r << 7));                                  \
            a0 += uasf(v[0] << 16); a1 += uasf(v[0] & 0xffff0000u);                     \
            a2 += uasf(v[1] << 16); a3 += uasf(v[1] & 0xffff0000u);                     \
        }                                                                               \
    }

#define AGGF_EPI(J)                                                                     \
    {                                                                                   \
        float iv = (end##J > 0) ? (1.0f / (float)end##J) : 0.f;                         \
        float m0 = a0 * iv, m1 = a1 * iv, m2 = a2 * iv, m3 = a3 * iv;                   \
        m0 = (m0 > 0.f) ? m0 : (__expf(m0) - 1.f);                                      \
        m1 = (m1 > 0.f) ? m1 : (__expf(m1) - 1.f);                                      \
        m2 = (m2 > 0.f) ? m2 : (__expf(m2) - 1.f);                                      \
        m3 = (m3 > 0.f) ? m3 : (__expf(m3) - 1.f);                                      \
        u32x2 hw;                                                                       \
        hw[0] = cvtpk(m0, m1);                                                          \
        hw[1] = cvtpk(m2, m3);                                                          \
        *(u32x2*)&h_lds[(w << 2) + J][lane << 2] = hw;                                  \
        a0 = a1 = a2 = a3 = 0.f;                                                        \
    }

#define WAIT4 asm volatile("s_waitcnt vmcnt(4)" ::: "memory"); __builtin_amdgcn_sched_barrier(0);

    float a0 = 0.f, a1 = 0.f, a2 = 0.f, a3 = 0.f;
    int gb = 0;

    AGGF_ISSUE(elv0, 0, 0); ++gb;
    for (int c = 1; c < nch0; ++c) {
        int b = gb & 1; AGGF_ISSUE(elv0, c, b); ++gb; WAIT4; AGGF_CONS(b ^ 1);
    }
    { int b = gb & 1; AGGF_ISSUE(elv1, 0, b); ++gb; WAIT4; AGGF_CONS(b ^ 1); AGGF_EPI(0); }
    for (int c = 1; c < nch1; ++c) {
        int b = gb & 1; AGGF_ISSUE(elv1, c, b); ++gb; WAIT4; AGGF_CONS(b ^ 1);
    }
    { int b = gb & 1; AGGF_ISSUE(elv2, 0, b); ++gb; WAIT4; AGGF_CONS(b ^ 1); AGGF_EPI(1); }
    for (int c = 1; c < nch2; ++c) {
        int b = gb & 1; AGGF_ISSUE(elv2, c, b); ++gb; WAIT4; AGGF_CONS(b ^ 1);
    }
    { int b = gb & 1; AGGF_ISSUE(elv3, 0, b); ++gb; WAIT4; AGGF_CONS(b ^ 1); AGGF_EPI(2); }
    for (int c = 1; c < nch3; ++c) {
        int b = gb & 1; AGGF_ISSUE(elv3, c, b); ++gb; WAIT4; AGGF_CONS(b ^ 1);
    }
    asm volatile("s_waitcnt vmcnt(0)" ::: "memory");
    __builtin_amdgcn_sched_barrier(0);
    { int b = (gb & 1) ^ 1; AGGF_CONS(b); AGGF_EPI(3); }

    __syncthreads();

    // fused gemm2: t2[16 nodes][64] = h[16][256] @ Bt2[64][256]^T ; wave w owns 16 cols
    {
        const int l15 = lane & 15, quad = lane >> 4;
        f32x4 acc = (f32x4){0.f, 0.f, 0.f, 0.f};
#pragma unroll
        for (int st = 0; st < 8; ++st) {
            short8 afr = *(const short8*)&h_lds[l15][st * 32 + quad * 8];
            short8 bfr = *(const short8*)(Bt2 + (size_t)(w * 16 + l15) * 256 + st * 32 + quad * 8);
            acc = __builtin_amdgcn_mfma_f32_16x16x32_bf16(afr, bfr, acc, 0, 0, 0);
        }
#pragma unroll
        for (int r = 0; r < 4; ++r)
            t2[(size_t)(s0b + quad * 4 + r) * 64 + w * 16 + l15] = f2bf1(acc[r]);
    }
}

// ---------------- agg2: full-row contiguous DMA gather over t2 (128B rows), R8 form ----------------

__global__ __launch_bounds__(256) void agg2_kernel(const unsigned short* __restrict__ t2,
                                                   const int* __restrict__ deg,
                                                   const unsigned short* __restrict__ sdst,
                                                   float* __restrict__ out) {
    __shared__ __align__(16) unsigned int ring[4][2][256];    // 4 waves x 2 bufs x 1KB = 8KB

    const int w    = __builtin_amdgcn_readfirstlane(threadIdx.x >> 6);
    const int lane = threadIdx.x & 63;
    const int s0   = blockIdx.x * 16 + w * 4;
    const unsigned int* tb32 = (const unsigned int*)t2;
    const unsigned int loff = ((unsigned)(lane & 7)) << 2;    // 16B chunk within a 128B row

    const int end0 = deg[s0 + 0], end1 = deg[s0 + 1], end2 = deg[s0 + 2], end3 = deg[s0 + 3];
    const int elv0 = sdst[(size_t)(s0 + 0) * SLOT + lane];
    const int elv1 = sdst[(size_t)(s0 + 1) * SLOT + lane];
    const int elv2 = sdst[(size_t)(s0 + 2) * SLOT + lane];
    const int elv3 = sdst[(size_t)(s0 + 3) * SLOT + lane];
    asm volatile("" :: "v"(end0), "v"(end1), "v"(end2), "v"(end3),
                       "v"(elv0), "v"(elv1), "v"(elv2), "v"(elv3));

#define AGG2_ISSUE(ELV, D, B)                                                           \
    {                                                                                   \
        int r = __shfl(ELV, ((D) << 3) + (lane >> 3));                                  \
        glds16(tb32 + (unsigned)r * 32u + loff, &ring[w][B][0]);                        \
    }

#define AGG2_CONSUME(B)                                                                 \
    {                                                                                   \
        const unsigned int* rbp = &ring[w][B][lane & 31];                               \
        _Pragma("unroll")                                                               \
        for (int i = 0; i < 4; ++i) {                                                   \
            unsigned int v = rbp[(((i << 1) + (lane >> 5)) << 5)];                      \
            a0 += uasf(v << 16); a1 += uasf(v & 0xffff0000u);                           \
        }                                                                               \
    }

#define AGG2_NODE(J)                                                                    \
    {                                                                                   \
        const int end = end##J;                                                         \
        const int nch = ((end + 7) & ~7) >> 3;                                          \
        float a0 = 0.f, a1 = 0.f;                                                       \
        if (nch > 0) {                                                                  \
            AGG2_ISSUE(elv##J, 0, 0);                                                   \
            for (int d = 1; d < nch; ++d) {                                             \
                AGG2_ISSUE(elv##J, d, d & 1);                                           \
                asm volatile("s_waitcnt vmcnt(1)" ::: "memory");                        \
                __builtin_amdgcn_sched_barrier(0);                                      \
                AGG2_CONSUME((d - 1) & 1);                                              \
            }                                                                           \
            asm volatile("s_waitcnt vmcnt(0)" ::: "memory");                            \
            __builtin_amdgcn_sched_barrier(0);                                          \
            AGG2_CONSUME((nch - 1) & 1);                                                \
        }                                                                               \
        a0 += __shfl_xor(a0, 32);                                                       \
        a1 += __shfl_xor(a1, 32);                                                       \
        if (lane < 32) {                                                                \
            float iv = (end > 0) ? (1.0f / (float)end) : 0.f;                           \
            f32x2 rr; rr.x = a0 * iv; rr.y = a1 * iv;                                   \
            *(f32x2*)(out + (size_t)(s0 + J) * D_OUT + (lane & 31) * 2) = rr;           \
        }                                                                               \
    }

    AGG2_NODE(0);
    AGG2_NODE(1);
    AGG2_NODE(2);
    AGG2_NODE(3);
}

// ---------------- launch ----------------

extern "C" void kernel_launch(void* const* d_in, const int* in_sizes, int n_in,
                              void* d_out, int out_size, void* d_ws, size_t ws_size,
                              hipStream_t stream) {
    const float* X  = (const float*)d_in[0];
    const int*   ei = (const int*)d_in[1];
    const float* W1 = (const float*)d_in[2];
    const float* W2 = (const float*)d_in[3];
    const int* src = ei;             // edge_index[0] = segment ids
    const int* dst = ei + N_EDGES;   // edge_index[1] = gathered neighbors

    char* ws = (char*)d_ws;
    size_t off = 0;
    auto alloc = [&](size_t bytes) {
        off = (off + 255) & ~(size_t)255;
        void* p = ws + off;
        off += bytes;
        return p;
    };
    int*          gcnt = (int*)alloc((size_t)NBUK * 4);
    unsigned int* gbuk = (unsigned int*)alloc((size_t)NBUK * MAXB * 4);
    unsigned short* sdst = (unsigned short*)alloc(((size_t)N_NODES * SLOT + 64) * 2);
    int*          deg  = (int*)alloc((size_t)N_NODES * 4);
    unsigned short* Bt1 = (unsigned short*)alloc((size_t)D_H1 * D_IN * 2);
    unsigned short* Bt2 = (unsigned short*)alloc((size_t)D_OUT * D_H1 * 2);
    unsigned short* t1  = (unsigned short*)alloc((size_t)NR * D_H1 * 2);
    unsigned short* t2  = (unsigned short*)alloc((size_t)NR * D_OUT * 2);

    hipMemsetAsync(gcnt, 0, (size_t)NBUK * 4, stream);

    pc_kernel<<<NPB + NCONVW, 256, 0, stream>>>(src, dst, gcnt, gbuk, W1, W2, Bt1, Bt2, t1, t2);
    sg_kernel<<<NBUK + NGEMM1, 512, 0, stream>>>(gcnt, gbuk, sdst, deg, X, Bt1, t1);
    aggf_kernel<<<N_NODES / 16, 256, 0, stream>>>(t1, deg, sdst, Bt2, t2);
    agg2_kernel<<<N_NODES / 16, 256, 0, stream>>>(t2, deg, sdst, (float*)d_out);
}